// Round 2
// baseline (774.959 us; speedup 1.0000x reference)
//
#include <hip/hip_runtime.h>
#include <math.h>

// ---------------- conv1 (5x5, 3->6) + relu + 2x2 maxpool ----------------
// x:[N,3,32,32] -> p1:[N,6,14,14]
__global__ __launch_bounds__(256) void k_conv1(const float* __restrict__ x,
                                               const float* __restrict__ w,
                                               const float* __restrict__ b,
                                               float* __restrict__ p1) {
    __shared__ float simg[4 * 3072];      // 4 images
    __shared__ float sw[6 * 3 * 28];      // (c*3+ci)*28 + (ky*5+kx), padded
    __shared__ float sb[6];
    const int tid = threadIdx.x;
    const int n0 = blockIdx.x * 4;

    const float4* xg = (const float4*)(x + (size_t)n0 * 3072);
    float4* sg = (float4*)simg;
    for (int i = tid; i < 3072; i += 256) sg[i] = xg[i];
    for (int i = tid; i < 450; i += 256) {          // FIX: was `if (tid < 450)` — only 256 threads!
        int c = i / 75, r = i % 75, ci = r / 25, k = r % 25;
        sw[(c * 3 + ci) * 28 + k] = w[i];
    }
    if (tid < 6) sb[tid] = b[tid];
    __syncthreads();

    for (int t = tid; t < 4 * 196; t += 256) {
        const int img = t / 196, pos = t % 196;
        const int py = pos / 14, px = pos % 14;
        const float* ib = simg + img * 3072;
        float acc[6][4];
        #pragma unroll
        for (int c = 0; c < 6; ++c) {
            acc[c][0] = 0.f; acc[c][1] = 0.f; acc[c][2] = 0.f; acc[c][3] = 0.f;
        }
        #pragma unroll
        for (int ci = 0; ci < 3; ++ci) {
            float patch[6][6];
            const float* pb = ib + ci * 1024 + (2 * py) * 32 + 2 * px;
            #pragma unroll
            for (int r = 0; r < 6; ++r) {
                float2 a0 = *(const float2*)(pb + r * 32);
                float2 a1 = *(const float2*)(pb + r * 32 + 2);
                float2 a2 = *(const float2*)(pb + r * 32 + 4);
                patch[r][0] = a0.x; patch[r][1] = a0.y; patch[r][2] = a1.x;
                patch[r][3] = a1.y; patch[r][4] = a2.x; patch[r][5] = a2.y;
            }
            #pragma unroll
            for (int c = 0; c < 6; ++c) {
                const float* wb = sw + (c * 3 + ci) * 28;
                #pragma unroll
                for (int ky = 0; ky < 5; ++ky) {
                    #pragma unroll
                    for (int kx = 0; kx < 5; ++kx) {
                        const float wv = wb[ky * 5 + kx];
                        acc[c][0] = fmaf(patch[ky][kx],         wv, acc[c][0]);
                        acc[c][1] = fmaf(patch[ky][kx + 1],     wv, acc[c][1]);
                        acc[c][2] = fmaf(patch[ky + 1][kx],     wv, acc[c][2]);
                        acc[c][3] = fmaf(patch[ky + 1][kx + 1], wv, acc[c][3]);
                    }
                }
            }
        }
        const int n = n0 + img;
        #pragma unroll
        for (int c = 0; c < 6; ++c) {
            float m = fmaxf(fmaxf(acc[c][0], acc[c][1]), fmaxf(acc[c][2], acc[c][3]));
            p1[((size_t)n * 6 + c) * 196 + pos] = fmaxf(m + sb[c], 0.f);
        }
    }
}

// ---------------- conv2 (5x5, 6->16) + relu + 2x2 maxpool ----------------
// p1:[N,6,14,14] -> p2:[N,400]  (c*25 + py*5 + px)
__global__ __launch_bounds__(256) void k_conv2(const float* __restrict__ p1,
                                               const float* __restrict__ w,
                                               const float* __restrict__ b,
                                               float* __restrict__ p2, int n_total) {
    __shared__ float sin_[10 * 1176];
    __shared__ float sw[16 * 6 * 28];     // (c*6+ci)*28 + k
    __shared__ float sb[16];
    const int tid = threadIdx.x;
    const int n0 = blockIdx.x * 10;
    const int nimg = min(10, n_total - n0);

    const float4* pg = (const float4*)(p1 + (size_t)n0 * 1176);
    float4* sg = (float4*)sin_;
    const int nf4 = nimg * 294;
    for (int i = tid; i < nf4; i += 256) sg[i] = pg[i];
    for (int i = tid; i < 2400; i += 256) {
        int c = i / 150, r = i % 150, ci = r / 25, k = r % 25;
        sw[(c * 6 + ci) * 28 + k] = w[i];
    }
    if (tid < 16) sb[tid] = b[tid];
    __syncthreads();

    const int ntask = nimg * 25;
    for (int t = tid; t < ntask; t += 256) {
        const int img = t / 25, pos = t % 25;
        const int py = pos / 5, px = pos % 5;
        const float* ib = sin_ + img * 1176;
        const int n = n0 + img;
        #pragma unroll
        for (int half = 0; half < 2; ++half) {
            float acc[8][4];
            #pragma unroll
            for (int c = 0; c < 8; ++c) {
                acc[c][0] = 0.f; acc[c][1] = 0.f; acc[c][2] = 0.f; acc[c][3] = 0.f;
            }
            #pragma unroll
            for (int ci = 0; ci < 6; ++ci) {
                float patch[6][6];
                const float* pb = ib + ci * 196 + (2 * py) * 14 + 2 * px;
                #pragma unroll
                for (int r = 0; r < 6; ++r) {
                    float2 a0 = *(const float2*)(pb + r * 14);
                    float2 a1 = *(const float2*)(pb + r * 14 + 2);
                    float2 a2 = *(const float2*)(pb + r * 14 + 4);
                    patch[r][0] = a0.x; patch[r][1] = a0.y; patch[r][2] = a1.x;
                    patch[r][3] = a1.y; patch[r][4] = a2.x; patch[r][5] = a2.y;
                }
                #pragma unroll
                for (int c8 = 0; c8 < 8; ++c8) {
                    const int c = half * 8 + c8;
                    const float* wb = sw + (c * 6 + ci) * 28;
                    #pragma unroll
                    for (int ky = 0; ky < 5; ++ky) {
                        #pragma unroll
                        for (int kx = 0; kx < 5; ++kx) {
                            const float wv = wb[ky * 5 + kx];
                            acc[c8][0] = fmaf(patch[ky][kx],         wv, acc[c8][0]);
                            acc[c8][1] = fmaf(patch[ky][kx + 1],     wv, acc[c8][1]);
                            acc[c8][2] = fmaf(patch[ky + 1][kx],     wv, acc[c8][2]);
                            acc[c8][3] = fmaf(patch[ky + 1][kx + 1], wv, acc[c8][3]);
                        }
                    }
                }
            }
            #pragma unroll
            for (int c8 = 0; c8 < 8; ++c8) {
                const int c = half * 8 + c8;
                float m = fmaxf(fmaxf(acc[c8][0], acc[c8][1]), fmaxf(acc[c8][2], acc[c8][3]));
                p2[(size_t)n * 400 + c * 25 + pos] = fmaxf(m + sb[c], 0.f);
            }
        }
    }
}

// ---------------- fc1: [N,400] @ [120,400]^T + relu -> h1:[N,120] ----------------
__global__ __launch_bounds__(256) void k_fc1(const float* __restrict__ p2,
                                             const float* __restrict__ w,
                                             const float* __restrict__ b,
                                             float* __restrict__ h1) {
    __shared__ float sa[64 * 100];
    __shared__ float swt[120 * 101];
    const int tid = threadIdx.x;
    const int n0 = blockIdx.x * 64;
    const int tc = tid % 30, tr = tid / 30;   // 240 active compute threads
    float acc[8][4];
    #pragma unroll
    for (int i = 0; i < 8; ++i)
        #pragma unroll
        for (int j = 0; j < 4; ++j) acc[i][j] = 0.f;

    for (int kt = 0; kt < 4; ++kt) {
        __syncthreads();
        for (int i = tid; i < 1600; i += 256) {
            int r = i / 25, k4 = (i % 25) * 4;
            float4 v = *(const float4*)(p2 + (size_t)(n0 + r) * 400 + kt * 100 + k4);
            *(float4*)(sa + r * 100 + k4) = v;
        }
        for (int i = tid; i < 3000; i += 256) {
            int c = i / 25, k4 = (i % 25) * 4;
            float4 v = *(const float4*)(w + (size_t)c * 400 + kt * 100 + k4);
            float* d = swt + c * 101 + k4;
            d[0] = v.x; d[1] = v.y; d[2] = v.z; d[3] = v.w;
        }
        __syncthreads();
        if (tr < 8) {
            #pragma unroll 4
            for (int k = 0; k < 100; ++k) {
                float av[8], wv[4];
                #pragma unroll
                for (int i = 0; i < 8; ++i) av[i] = sa[(tr * 8 + i) * 100 + k];
                #pragma unroll
                for (int j = 0; j < 4; ++j) wv[j] = swt[(tc * 4 + j) * 101 + k];
                #pragma unroll
                for (int i = 0; i < 8; ++i)
                    #pragma unroll
                    for (int j = 0; j < 4; ++j) acc[i][j] = fmaf(av[i], wv[j], acc[i][j]);
            }
        }
    }
    if (tr < 8) {
        #pragma unroll
        for (int j = 0; j < 4; ++j) {
            const int o = tc * 4 + j;
            const float bo = b[o];
            #pragma unroll
            for (int i = 0; i < 8; ++i) {
                const int rr = n0 + tr * 8 + i;
                h1[(size_t)rr * 120 + o] = fmaxf(acc[i][j] + bo, 0.f);
            }
        }
    }
}

// ---------------- compose: C[e][o][d] = sum_j head_w[o][j]*expert_w[e][j][d] ----------------
__global__ __launch_bounds__(256) void k_compose(const float* __restrict__ ew,
                                                 const float* __restrict__ eb,
                                                 const float* __restrict__ hw,
                                                 float* __restrict__ C,
                                                 float* __restrict__ hb2) {
    __shared__ float shw[840];
    __shared__ float seb[672];
    const int e = blockIdx.x, tid = threadIdx.x;
    for (int i = tid; i < 840; i += 256) shw[i] = hw[i];
    for (int i = tid; i < 672; i += 256) seb[i] = eb[i];
    __syncthreads();
    for (int i = tid; i < 840; i += 256) {
        int o = i / 84, d = i % 84;
        float s = 0.f;
        for (int j = 0; j < 84; ++j)
            s = fmaf(shw[o * 84 + j], ew[((size_t)e * 84 + j) * 84 + d], s);
        C[e * 840 + i] = s;
    }
    if (tid < 10) {
        float s = 0.f;
        for (int j = 0; j < 84; ++j) s = fmaf(shw[tid * 84 + j], seb[e * 84 + j], s);
        hb2[e * 10 + tid] = s;
    }
}

// ---------------- tail: fc2+relu, gate, top2-softmax, MoE(composed)+head ----------------
__global__ __launch_bounds__(256) void k_tail(const float* __restrict__ h1,
                                              const float* __restrict__ f2w,
                                              const float* __restrict__ f2b,
                                              const float* __restrict__ gw,
                                              const float* __restrict__ Cw,
                                              const float* __restrict__ hb2,
                                              const float* __restrict__ headb,
                                              float* __restrict__ out) {
    __shared__ float sh1[64 * 120];
    __shared__ float sfw[84 * 121];
    __shared__ float sfb[84];
    __shared__ float sgw[672];
    __shared__ float sh[64 * 85];
    __shared__ float sC[6800];           // [(e*10+o)*85 + d]
    __shared__ float shb2[80];
    __shared__ float shb[10];
    __shared__ float slog[64 * 9];
    __shared__ float swt[128];
    __shared__ int   sei[128];
    const int tid = threadIdx.x;
    const int n0 = blockIdx.x * 64;

    {
        const float4* g = (const float4*)(h1 + (size_t)n0 * 120);
        float4* s = (float4*)sh1;
        for (int i = tid; i < 1920; i += 256) s[i] = g[i];
    }
    for (int i = tid; i < 2520; i += 256) {
        int o = i / 30, k4 = (i % 30) * 4;
        float4 v = *(const float4*)(f2w + (size_t)o * 120 + k4);
        float* d = sfw + o * 121 + k4;
        d[0] = v.x; d[1] = v.y; d[2] = v.z; d[3] = v.w;
    }
    for (int i = tid; i < 6720; i += 256) sC[(i / 84) * 85 + (i % 84)] = Cw[i];
    for (int i = tid; i < 672; i += 256) sgw[i] = gw[i];
    if (tid < 84) sfb[tid] = f2b[tid];
    if (tid < 80) shb2[tid] = hb2[tid];
    if (tid < 10) shb[tid] = headb[tid];
    __syncthreads();

    // fc2 + relu
    for (int i = tid; i < 5376; i += 256) {
        const int t = i / 84, o = i % 84;
        const float* a = sh1 + t * 120;
        const float* wr = sfw + o * 121;
        float s = 0.f;
        #pragma unroll 8
        for (int k = 0; k < 120; ++k) s = fmaf(a[k], wr[k], s);
        sh[t * 85 + o] = fmaxf(s + sfb[o], 0.f);
    }
    __syncthreads();

    // gate logits
    for (int i = tid; i < 512; i += 256) {
        const int t = i / 8, e = i % 8;
        const float* a = sh + t * 85;
        float s = 0.f;
        #pragma unroll 4
        for (int d = 0; d < 84; ++d) s = fmaf(a[d], sgw[d * 8 + e], s);
        slog[t * 9 + e] = s;
    }
    __syncthreads();

    // top-2 softmax (equivalent to softmax -> top_k -> renorm)
    if (tid < 64) {
        const float* l = slog + tid * 9;
        float m1 = l[0]; int i1 = 0;
        #pragma unroll
        for (int e = 1; e < 8; ++e) if (l[e] > m1) { m1 = l[e]; i1 = e; }
        float m2 = -1e30f; int i2 = 0;
        #pragma unroll
        for (int e = 0; e < 8; ++e) if (e != i1 && l[e] > m2) { m2 = l[e]; i2 = e; }
        const float r = expf(m2 - m1);
        const float inv = 1.f / (1.f + r);
        swt[tid * 2] = inv; swt[tid * 2 + 1] = r * inv;
        sei[tid * 2] = i1; sei[tid * 2 + 1] = i2;
    }
    __syncthreads();

    // combine + head
    for (int i = tid; i < 640; i += 256) {
        const int t = i / 10, o = i % 10;
        const float* a = sh + t * 85;
        const float w0 = swt[t * 2], w1 = swt[t * 2 + 1];
        const int e0 = sei[t * 2], e1 = sei[t * 2 + 1];
        const float* c0 = sC + (e0 * 10 + o) * 85;
        const float* c1 = sC + (e1 * 10 + o) * 85;
        float s0 = 0.f, s1 = 0.f;
        #pragma unroll 4
        for (int d = 0; d < 84; ++d) {
            s0 = fmaf(a[d], c0[d], s0);
            s1 = fmaf(a[d], c1[d], s1);
        }
        out[(size_t)(n0 + t) * 10 + o] =
            shb[o] + w0 * (s0 + shb2[e0 * 10 + o]) + w1 * (s1 + shb2[e1 * 10 + o]);
    }
}

extern "C" void kernel_launch(void* const* d_in, const int* in_sizes, int n_in,
                              void* d_out, int out_size, void* d_ws, size_t ws_size,
                              hipStream_t stream) {
    const float* x   = (const float*)d_in[0];
    const float* c1w = (const float*)d_in[1];
    const float* c1b = (const float*)d_in[2];
    const float* c2w = (const float*)d_in[3];
    const float* c2b = (const float*)d_in[4];
    const float* f1w = (const float*)d_in[5];
    const float* f1b = (const float*)d_in[6];
    const float* f2w = (const float*)d_in[7];
    const float* f2b = (const float*)d_in[8];
    const float* gw  = (const float*)d_in[9];
    const float* ew  = (const float*)d_in[10];
    const float* eb  = (const float*)d_in[11];
    const float* hw  = (const float*)d_in[12];
    const float* hb  = (const float*)d_in[13];
    float* out = (float*)d_out;

    const int N = in_sizes[0] / 3072;   // 16384

    float* ws = (float*)d_ws;
    float* p1  = ws;                          // N*1176
    float* p2  = p1 + (size_t)N * 1176;       // N*400
    float* h1  = p2 + (size_t)N * 400;        // N*120
    float* C   = h1 + (size_t)N * 120;        // 6720
    float* hb2 = C + 6720;                    // 80

    k_conv1<<<N / 4, 256, 0, stream>>>(x, c1w, c1b, p1);
    k_conv2<<<(N + 9) / 10, 256, 0, stream>>>(p1, c2w, c2b, p2, N);
    k_fc1<<<N / 64, 256, 0, stream>>>(p2, f1w, f1b, h1);
    k_compose<<<8, 256, 0, stream>>>(ew, eb, hw, C, hb2);
    k_tail<<<N / 64, 256, 0, stream>>>(h1, f2w, f2b, gw, C, hb2, hb, out);
}

// Round 4
// 485.441 us; speedup vs baseline: 1.5964x; 1.5964x over previous
//
#include <hip/hip_runtime.h>
#include <math.h>

typedef _Float16 half8 __attribute__((ext_vector_type(8)));
typedef float f32x4 __attribute__((ext_vector_type(4)));

// split fp32 -> (hi,lo) fp16 pair packed in one uint (hi in low 16, lo in high 16)
__device__ inline uint splitpack(float v) {
    _Float16 h = (_Float16)v;
    float r = v - (float)h;
    _Float16 l = (_Float16)r;
    return (uint)__builtin_bit_cast(unsigned short, h) |
           ((uint)__builtin_bit_cast(unsigned short, l) << 16);
}
__device__ inline _Float16 lo16h(uint u) { return __builtin_bit_cast(_Float16, (unsigned short)(u & 0xffffu)); }
__device__ inline _Float16 hi16h(uint u) { return __builtin_bit_cast(_Float16, (unsigned short)(u >> 16)); }

// ---------------- conv1 via split-fp16 MFMA: x:[N,3,32,32] -> p1:[N,6,14,14] packed uint ----------------
// GEMM per image: M = 196 quads * 4 (pool-quad row order), K = 75 pad 96, N = 6 of 16.
__global__ __launch_bounds__(256) void k_conv1(const float* __restrict__ x,
                                               const float* __restrict__ w,
                                               const float* __restrict__ b,
                                               uint* __restrict__ p1) {
    __shared__ uint simg[4 * 3072];       // 48 KB, packed hi/lo
    __shared__ uint sB[3 * 64 * 8];       // 6 KB
    __shared__ float sb[6];
    const int tid  = threadIdx.x;
    const int lane = tid & 63;
    const int wv   = tid >> 6;
    const int n0   = blockIdx.x * 4;

    {
        const float4* xg = (const float4*)(x + (size_t)n0 * 3072);
        uint4* sg = (uint4*)simg;
        for (int i = tid; i < 3072; i += 256) {
            float4 v = xg[i];
            uint4 u;
            u.x = splitpack(v.x); u.y = splitpack(v.y);
            u.z = splitpack(v.z); u.w = splitpack(v.w);
            sg[i] = u;
        }
    }
    for (int p = tid; p < 192; p += 256) {
        int ks = p >> 6, l = p & 63;
        int n = l & 15, g = l >> 4;
        #pragma unroll
        for (int j = 0; j < 8; ++j) {
            int k = ks * 32 + g * 8 + j;
            float wv_ = (n < 6 && k < 75) ? w[n * 75 + k] : 0.f;
            sB[p * 8 + j] = splitpack(wv_);
        }
    }
    if (tid < 6) sb[tid] = b[tid];
    __syncthreads();

    const int qw = (lane & 15) >> 2;
    const int dy = (lane >> 1) & 1, dx = lane & 1;
    const int g  = lane >> 4;
    int offs[24];
    #pragma unroll
    for (int ks = 0; ks < 3; ++ks)
        #pragma unroll
        for (int j = 0; j < 8; ++j) {
            int k = ks * 32 + g * 8 + j;
            int o = 0;
            if (k < 75) { int ci = k / 25, r = k % 25; o = ci * 1024 + (r / 5) * 32 + (r % 5); }
            offs[ks * 8 + j] = o;
        }
    half8 bh[3], bl[3];
    #pragma unroll
    for (int ks = 0; ks < 3; ++ks)
        #pragma unroll
        for (int j = 0; j < 8; ++j) {
            uint u = sB[(ks * 64 + lane) * 8 + j];
            bh[ks][j] = lo16h(u); bl[ks][j] = hi16h(u);
        }

    const uint* img = simg + wv * 3072;
    const int n  = n0 + wv;
    const int cc = lane & 15;
    const int qr = lane >> 4;
    const float bias = (cc < 6) ? sb[cc] : 0.f;
    uint* outb = p1 + ((size_t)n * 6 + cc) * 196;

    for (int t = 0; t < 49; ++t) {
        int q  = t * 4 + qw;
        int qy = q / 14, qx = q % 14;
        int base = (2 * qy + dy) * 32 + (2 * qx + dx);
        f32x4 acc = {0.f, 0.f, 0.f, 0.f};
        #pragma unroll
        for (int ks = 0; ks < 3; ++ks) {
            uint up[8];
            #pragma unroll
            for (int j = 0; j < 8; ++j) up[j] = img[base + offs[ks * 8 + j]];
            half8 ah, al;
            #pragma unroll
            for (int j = 0; j < 8; ++j) { ah[j] = lo16h(up[j]); al[j] = hi16h(up[j]); }
            acc = __builtin_amdgcn_mfma_f32_16x16x32_f16(al, bl[ks], acc, 0, 0, 0);
            acc = __builtin_amdgcn_mfma_f32_16x16x32_f16(al, bh[ks], acc, 0, 0, 0);
            acc = __builtin_amdgcn_mfma_f32_16x16x32_f16(ah, bl[ks], acc, 0, 0, 0);
            acc = __builtin_amdgcn_mfma_f32_16x16x32_f16(ah, bh[ks], acc, 0, 0, 0);
        }
        if (cc < 6) {
            float m = fmaxf(fmaxf(acc[0], acc[1]), fmaxf(acc[2], acc[3]));
            outb[t * 4 + qr] = splitpack(fmaxf(m + bias, 0.f));
        }
    }
}

// ---------------- conv2 via split-fp16 MFMA: p1 packed -> p2:[N,400] fp32 ----------------
// GEMM per image: M = 25 quads * 4 (pad to 7 tiles), K = 150 pad 160, N = 16 exact.
__global__ __launch_bounds__(256) void k_conv2(const uint* __restrict__ p1,
                                               const float* __restrict__ w,
                                               const float* __restrict__ b,
                                               float* __restrict__ p2) {
    __shared__ uint simg[4 * 1176];       // 18.4 KB packed
    __shared__ uint sB[5 * 64 * 8];       // 10 KB
    __shared__ float sb[16];
    const int tid  = threadIdx.x;
    const int lane = tid & 63;
    const int wv   = tid >> 6;
    const int n0   = blockIdx.x * 4;

    {
        const uint4* pg = (const uint4*)(p1 + (size_t)n0 * 1176);
        uint4* sg = (uint4*)simg;
        for (int i = tid; i < 1176; i += 256) sg[i] = pg[i];
    }
    for (int p = tid; p < 320; p += 256) {
        int ks = p >> 6, l = p & 63;
        int n = l & 15, g = l >> 4;
        #pragma unroll
        for (int j = 0; j < 8; ++j) {
            int k = ks * 32 + g * 8 + j;
            float wv_ = (k < 150) ? w[n * 150 + k] : 0.f;
            sB[p * 8 + j] = splitpack(wv_);
        }
    }
    if (tid < 16) sb[tid] = b[tid];
    __syncthreads();

    const int qw = (lane & 15) >> 2;
    const int dy = (lane >> 1) & 1, dx = lane & 1;
    const int g  = lane >> 4;
    int offs[40];
    #pragma unroll
    for (int ks = 0; ks < 5; ++ks)
        #pragma unroll
        for (int j = 0; j < 8; ++j) {
            int k = ks * 32 + g * 8 + j;
            int o = 0;
            if (k < 150) { int ci = k / 25, r = k % 25; o = ci * 196 + (r / 5) * 14 + (r % 5); }
            offs[ks * 8 + j] = o;
        }
    half8 bh[5], bl[5];
    #pragma unroll
    for (int ks = 0; ks < 5; ++ks)
        #pragma unroll
        for (int j = 0; j < 8; ++j) {
            uint u = sB[(ks * 64 + lane) * 8 + j];
            bh[ks][j] = lo16h(u); bl[ks][j] = hi16h(u);
        }

    const uint* img = simg + wv * 1176;
    const int n  = n0 + wv;
    const int cc = lane & 15;
    const int qr = lane >> 4;
    const float bias = sb[cc];
    float* outb = p2 + (size_t)n * 400 + cc * 25;

    for (int t = 0; t < 7; ++t) {
        int qa = t * 4 + qw; if (qa > 24) qa = 24;
        int qy = qa / 5, qx = qa % 5;
        int base = (2 * qy + dy) * 14 + (2 * qx + dx);
        f32x4 acc = {0.f, 0.f, 0.f, 0.f};
        #pragma unroll
        for (int ks = 0; ks < 5; ++ks) {
            uint up[8];
            #pragma unroll
            for (int j = 0; j < 8; ++j) up[j] = img[base + offs[ks * 8 + j]];
            half8 ah, al;
            #pragma unroll
            for (int j = 0; j < 8; ++j) { ah[j] = lo16h(up[j]); al[j] = hi16h(up[j]); }
            acc = __builtin_amdgcn_mfma_f32_16x16x32_f16(al, bl[ks], acc, 0, 0, 0);
            acc = __builtin_amdgcn_mfma_f32_16x16x32_f16(al, bh[ks], acc, 0, 0, 0);
            acc = __builtin_amdgcn_mfma_f32_16x16x32_f16(ah, bl[ks], acc, 0, 0, 0);
            acc = __builtin_amdgcn_mfma_f32_16x16x32_f16(ah, bh[ks], acc, 0, 0, 0);
        }
        int qc = t * 4 + qr;
        if (qc < 25) {
            float m = fmaxf(fmaxf(acc[0], acc[1]), fmaxf(acc[2], acc[3]));
            outb[qc] = fmaxf(m + bias, 0.f);
        }
    }
}

// ---------------- fc1: [N,400] @ [120,400]^T + relu -> h1:[N,120] ----------------
__global__ __launch_bounds__(256) void k_fc1(const float* __restrict__ p2,
                                             const float* __restrict__ w,
                                             const float* __restrict__ b,
                                             float* __restrict__ h1) {
    __shared__ float sa[64 * 100];
    __shared__ float swt[120 * 101];
    const int tid = threadIdx.x;
    const int n0 = blockIdx.x * 64;
    const int tc = tid % 30, tr = tid / 30;
    float acc[8][4];
    #pragma unroll
    for (int i = 0; i < 8; ++i)
        #pragma unroll
        for (int j = 0; j < 4; ++j) acc[i][j] = 0.f;

    for (int kt = 0; kt < 4; ++kt) {
        __syncthreads();
        for (int i = tid; i < 1600; i += 256) {
            int r = i / 25, k4 = (i % 25) * 4;
            float4 v = *(const float4*)(p2 + (size_t)(n0 + r) * 400 + kt * 100 + k4);
            *(float4*)(sa + r * 100 + k4) = v;
        }
        for (int i = tid; i < 3000; i += 256) {
            int c = i / 25, k4 = (i % 25) * 4;
            float4 v = *(const float4*)(w + (size_t)c * 400 + kt * 100 + k4);
            float* d = swt + c * 101 + k4;
            d[0] = v.x; d[1] = v.y; d[2] = v.z; d[3] = v.w;
        }
        __syncthreads();
        if (tr < 8) {
            #pragma unroll 4
            for (int k = 0; k < 100; ++k) {
                float av[8], wv[4];
                #pragma unroll
                for (int i = 0; i < 8; ++i) av[i] = sa[(tr * 8 + i) * 100 + k];
                #pragma unroll
                for (int j = 0; j < 4; ++j) wv[j] = swt[(tc * 4 + j) * 101 + k];
                #pragma unroll
                for (int i = 0; i < 8; ++i)
                    #pragma unroll
                    for (int j = 0; j < 4; ++j) acc[i][j] = fmaf(av[i], wv[j], acc[i][j]);
            }
        }
    }
    if (tr < 8) {
        #pragma unroll
        for (int j = 0; j < 4; ++j) {
            const int o = tc * 4 + j;
            const float bo = b[o];
            #pragma unroll
            for (int i = 0; i < 8; ++i) {
                const int rr = n0 + tr * 8 + i;
                h1[(size_t)rr * 120 + o] = fmaxf(acc[i][j] + bo, 0.f);
            }
        }
    }
}

// ---------------- compose: C[e][o][d] = sum_j head_w[o][j]*expert_w[e][j][d] ----------------
__global__ __launch_bounds__(256) void k_compose(const float* __restrict__ ew,
                                                 const float* __restrict__ eb,
                                                 const float* __restrict__ hw,
                                                 float* __restrict__ C,
                                                 float* __restrict__ hb2) {
    __shared__ float shw[840];
    __shared__ float seb[672];
    const int e = blockIdx.x, tid = threadIdx.x;
    for (int i = tid; i < 840; i += 256) shw[i] = hw[i];
    for (int i = tid; i < 672; i += 256) seb[i] = eb[i];
    __syncthreads();
    for (int i = tid; i < 840; i += 256) {
        int o = i / 84, d = i % 84;
        float s = 0.f;
        for (int j = 0; j < 84; ++j)
            s = fmaf(shw[o * 84 + j], ew[((size_t)e * 84 + j) * 84 + d], s);
        C[e * 840 + i] = s;
    }
    if (tid < 10) {
        float s = 0.f;
        for (int j = 0; j < 84; ++j) s = fmaf(shw[tid * 84 + j], seb[e * 84 + j], s);
        hb2[e * 10 + tid] = s;
    }
}

// ---------------- tail: fc2+relu, gate, top2-softmax, MoE(composed)+head ----------------
__global__ __launch_bounds__(256) void k_tail(const float* __restrict__ h1,
                                              const float* __restrict__ f2w,
                                              const float* __restrict__ f2b,
                                              const float* __restrict__ gw,
                                              const float* __restrict__ Cw,
                                              const float* __restrict__ hb2,
                                              const float* __restrict__ headb,
                                              float* __restrict__ out) {
    __shared__ float sh1[64 * 120];
    __shared__ float sfw[84 * 121];
    __shared__ float sfb[84];
    __shared__ float sgw[672];
    __shared__ float sh[64 * 85];
    __shared__ float sC[6800];
    __shared__ float shb2[80];
    __shared__ float shb[10];
    __shared__ float slog[64 * 9];
    __shared__ float swt[128];
    __shared__ int   sei[128];
    const int tid = threadIdx.x;
    const int n0 = blockIdx.x * 64;

    {
        const float4* g = (const float4*)(h1 + (size_t)n0 * 120);
        float4* s = (float4*)sh1;
        for (int i = tid; i < 1920; i += 256) s[i] = g[i];
    }
    for (int i = tid; i < 2520; i += 256) {
        int o = i / 30, k4 = (i % 30) * 4;
        float4 v = *(const float4*)(f2w + (size_t)o * 120 + k4);
        float* d = sfw + o * 121 + k4;
        d[0] = v.x; d[1] = v.y; d[2] = v.z; d[3] = v.w;
    }
    for (int i = tid; i < 6720; i += 256) sC[(i / 84) * 85 + (i % 84)] = Cw[i];
    for (int i = tid; i < 672; i += 256) sgw[i] = gw[i];
    if (tid < 84) sfb[tid] = f2b[tid];
    if (tid < 80) shb2[tid] = hb2[tid];
    if (tid < 10) shb[tid] = headb[tid];
    __syncthreads();

    for (int i = tid; i < 5376; i += 256) {
        const int t = i / 84, o = i % 84;
        const float* a = sh1 + t * 120;
        const float* wr = sfw + o * 121;
        float s = 0.f;
        #pragma unroll 8
        for (int k = 0; k < 120; ++k) s = fmaf(a[k], wr[k], s);
        sh[t * 85 + o] = fmaxf(s + sfb[o], 0.f);
    }
    __syncthreads();

    for (int i = tid; i < 512; i += 256) {
        const int t = i / 8, e = i % 8;
        const float* a = sh + t * 85;
        float s = 0.f;
        #pragma unroll 4
        for (int d = 0; d < 84; ++d) s = fmaf(a[d], sgw[d * 8 + e], s);
        slog[t * 9 + e] = s;
    }
    __syncthreads();

    if (tid < 64) {
        const float* l = slog + tid * 9;
        float m1 = l[0]; int i1 = 0;
        #pragma unroll
        for (int e = 1; e < 8; ++e) if (l[e] > m1) { m1 = l[e]; i1 = e; }
        float m2 = -1e30f; int i2 = 0;
        #pragma unroll
        for (int e = 0; e < 8; ++e) if (e != i1 && l[e] > m2) { m2 = l[e]; i2 = e; }
        const float r = expf(m2 - m1);
        const float inv = 1.f / (1.f + r);
        swt[tid * 2] = inv; swt[tid * 2 + 1] = r * inv;
        sei[tid * 2] = i1; sei[tid * 2 + 1] = i2;
    }
    __syncthreads();

    for (int i = tid; i < 640; i += 256) {
        const int t = i / 10, o = i % 10;
        const float* a = sh + t * 85;
        const float w0 = swt[t * 2], w1 = swt[t * 2 + 1];
        const int e0 = sei[t * 2], e1 = sei[t * 2 + 1];
        const float* c0 = sC + (e0 * 10 + o) * 85;
        const float* c1 = sC + (e1 * 10 + o) * 85;
        float s0 = 0.f, s1 = 0.f;
        #pragma unroll 4
        for (int d = 0; d < 84; ++d) {
            s0 = fmaf(a[d], c0[d], s0);
            s1 = fmaf(a[d], c1[d], s1);
        }
        out[(size_t)(n0 + t) * 10 + o] =
            shb[o] + w0 * (s0 + shb2[e0 * 10 + o]) + w1 * (s1 + shb2[e1 * 10 + o]);
    }
}

extern "C" void kernel_launch(void* const* d_in, const int* in_sizes, int n_in,
                              void* d_out, int out_size, void* d_ws, size_t ws_size,
                              hipStream_t stream) {
    const float* x   = (const float*)d_in[0];
    const float* c1w = (const float*)d_in[1];
    const float* c1b = (const float*)d_in[2];
    const float* c2w = (const float*)d_in[3];
    const float* c2b = (const float*)d_in[4];
    const float* f1w = (const float*)d_in[5];
    const float* f1b = (const float*)d_in[6];
    const float* f2w = (const float*)d_in[7];
    const float* f2b = (const float*)d_in[8];
    const float* gw  = (const float*)d_in[9];
    const float* ew  = (const float*)d_in[10];
    const float* eb  = (const float*)d_in[11];
    const float* hw  = (const float*)d_in[12];
    const float* hb  = (const float*)d_in[13];
    float* out = (float*)d_out;

    const int N = in_sizes[0] / 3072;   // 16384

    float* ws = (float*)d_ws;
    uint*  p1  = (uint*)ws;                    // N*1176 uints (packed hi/lo)
    float* p2  = ws + (size_t)N * 1176;        // N*400
    float* h1  = p2 + (size_t)N * 400;         // N*120
    float* C   = h1 + (size_t)N * 120;         // 6720
    float* hb2 = C + 6720;                     // 80

    k_conv1<<<N / 4, 256, 0, stream>>>(x, c1w, c1b, p1);
    k_conv2<<<N / 4, 256, 0, stream>>>(p1, c2w, c2b, p2);
    k_fc1<<<N / 64, 256, 0, stream>>>(p2, f1w, f1b, h1);
    k_compose<<<8, 256, 0, stream>>>(ew, eb, hw, C, hb2);
    k_tail<<<N / 64, 256, 0, stream>>>(h1, f2w, f2b, gw, C, hb2, hb, out);
}

// Round 5
// 417.849 us; speedup vs baseline: 1.8546x; 1.1618x over previous
//
#include <hip/hip_runtime.h>
#include <math.h>

typedef _Float16 half8 __attribute__((ext_vector_type(8)));
typedef float f32x4 __attribute__((ext_vector_type(4)));

// split fp32 -> (hi,lo) fp16 pair packed in one uint (hi in low 16, lo in high 16)
__device__ inline uint splitpack(float v) {
    _Float16 h = (_Float16)v;
    float r = v - (float)h;
    _Float16 l = (_Float16)r;
    return (uint)__builtin_bit_cast(unsigned short, h) |
           ((uint)__builtin_bit_cast(unsigned short, l) << 16);
}
__device__ inline _Float16 lo16h(uint u) { return __builtin_bit_cast(_Float16, (unsigned short)(u & 0xffffu)); }
__device__ inline _Float16 hi16h(uint u) { return __builtin_bit_cast(_Float16, (unsigned short)(u >> 16)); }

// ---------------- conv1 via split-fp16 MFMA, dx-in-N formulation ----------------
// x:[N,3,32,32] -> p1:[N,6,14,14] packed uint.
// Per image GEMM: M = 392 rows (r = qx*28 + y), N cols = dx*8 + c (12 of 16 used),
// K = 90 (k = ci*30 + ky*6 + kxp) pad 96.  B[(ci,ky,kxp)][(dx,c)] = w[c][ci][ky][kxp-dx].
// LDS image rows padded to stride 33 -> conflict-free gathers.
__global__ __launch_bounds__(256) void k_conv1(const float* __restrict__ x,
                                               const float* __restrict__ w,
                                               const float* __restrict__ b,
                                               uint* __restrict__ p1) {
    __shared__ uint simg[4 * 3168];       // 4 imgs, [ci][32][33] padded, 50688 B
    __shared__ uint sB[3 * 64 * 8];       // 6144 B
    __shared__ float sb[6];
    const int tid  = threadIdx.x;
    const int lane = tid & 63;
    const int wv   = tid >> 6;
    const int n0   = blockIdx.x * 4;

    // stage 4 images fp32 -> packed split-fp16, padded rows
    for (int i = tid; i < 3072; i += 256) {
        int img = i >> 10;                 // i/1024 ... careful: 3072 f4 total = 768/img
        img = i / 768;
        int rem = i - img * 768;           // float4 index within image
        int plane = rem >> 8;              // /256
        int rr = (rem & 255) >> 3;         // row
        int c4 = (rem & 7) << 2;           // col start
        float4 v = *(const float4*)(x + ((size_t)(n0 + img) * 3 + plane) * 1024 + rr * 32 + c4);
        uint* d = simg + img * 3168 + plane * 1056 + rr * 33 + c4;
        d[0] = splitpack(v.x); d[1] = splitpack(v.y);
        d[2] = splitpack(v.z); d[3] = splitpack(v.w);
    }
    // B fragments
    for (int p = tid; p < 192; p += 256) {
        int ks = p >> 6, l = p & 63;
        int col = l & 15, g = l >> 4;
        int c = col & 7, dx = col >> 3;
        #pragma unroll
        for (int j = 0; j < 8; ++j) {
            int k = ks * 32 + g * 8 + j;
            float val = 0.f;
            if (k < 90 && c < 6) {
                int ci = k / 30, rem = k % 30, ky = rem / 6, kxp = rem % 6;
                int kx = kxp - dx;
                if (kx >= 0 && kx < 5) val = w[c * 75 + ci * 25 + ky * 5 + kx];
            }
            sB[p * 8 + j] = splitpack(val);
        }
    }
    if (tid < 6) sb[tid] = b[tid];
    __syncthreads();

    const int g = lane >> 4;
    int offs[24];
    #pragma unroll
    for (int ks = 0; ks < 3; ++ks)
        #pragma unroll
        for (int j = 0; j < 8; ++j) {
            int k = ks * 32 + g * 8 + j;
            int o = 0;
            if (k < 90) { int ci = k / 30, rem = k % 30; o = ci * 1056 + (rem / 6) * 33 + (rem % 6); }
            offs[ks * 8 + j] = o;
        }
    half8 bh[3], bl[3];
    #pragma unroll
    for (int ks = 0; ks < 3; ++ks)
        #pragma unroll
        for (int j = 0; j < 8; ++j) {
            uint u = sB[(ks * 64 + lane) * 8 + j];
            bh[ks][j] = lo16h(u); bl[ks][j] = hi16h(u);
        }

    const int n   = n0 + wv;
    const int col = lane & 15;
    const int c   = col & 7, dx = col >> 3;
    const int qr  = lane >> 4;
    const float bias = (c < 6) ? sb[c] : 0.f;
    uint* outb = p1 + ((size_t)n * 6 + c) * 196;
    const uint* img = simg + wv * 3168;

    for (int t = 0; t < 25; ++t) {
        int r = t * 16 + col; if (r > 391) r = 391;
        int qx = r / 28, y = r - qx * 28;
        int base2 = y * 33 + 2 * qx;
        f32x4 acc = {0.f, 0.f, 0.f, 0.f};
        #pragma unroll
        for (int ks = 0; ks < 3; ++ks) {
            uint up[8];
            #pragma unroll
            for (int j = 0; j < 8; ++j) up[j] = img[base2 + offs[ks * 8 + j]];
            half8 ah, al;
            #pragma unroll
            for (int j = 0; j < 8; ++j) { ah[j] = lo16h(up[j]); al[j] = hi16h(up[j]); }
            acc = __builtin_amdgcn_mfma_f32_16x16x32_f16(al, bl[ks], acc, 0, 0, 0);
            acc = __builtin_amdgcn_mfma_f32_16x16x32_f16(al, bh[ks], acc, 0, 0, 0);
            acc = __builtin_amdgcn_mfma_f32_16x16x32_f16(ah, bl[ks], acc, 0, 0, 0);
            acc = __builtin_amdgcn_mfma_f32_16x16x32_f16(ah, bh[ks], acc, 0, 0, 0);
        }
        // pool: y-pairs in regs, dx-partner across lane^8
        float m01 = fmaxf(acc[0], acc[1]);
        float m23 = fmaxf(acc[2], acc[3]);
        float p01 = fmaxf(m01, __shfl_xor(m01, 8, 64));
        float p23 = fmaxf(m23, __shfl_xor(m23, 8, 64));
        if (dx == 0 && c < 6) {
            int r0 = t * 16 + qr * 4;
            if (r0 + 1 < 392) {
                int qx0 = r0 / 28, y0 = r0 - qx0 * 28;
                outb[(y0 >> 1) * 14 + qx0] = splitpack(fmaxf(p01 + bias, 0.f));
            }
            int r2 = r0 + 2;
            if (r2 + 1 < 392) {
                int qx2 = r2 / 28, y2 = r2 - qx2 * 28;
                outb[(y2 >> 1) * 14 + qx2] = splitpack(fmaxf(p23 + bias, 0.f));
            }
        }
    }
}

// ---------------- conv2 via split-fp16 MFMA: p1 packed -> p2:[N,400] fp32 ----------------
// GEMM per image: M = 25 quads * 4 (pad to 7 tiles), K = 150 pad 160, N = 16 exact.
// LDS image rows padded to stride 15 (plane 210, img 1260).
__global__ __launch_bounds__(256) void k_conv2(const uint* __restrict__ p1,
                                               const float* __restrict__ w,
                                               const float* __restrict__ b,
                                               float* __restrict__ p2) {
    __shared__ uint simg[4 * 1260];       // 20160 B
    __shared__ uint sB[5 * 64 * 8];       // 10240 B
    __shared__ float sb[16];
    const int tid  = threadIdx.x;
    const int lane = tid & 63;
    const int wv   = tid >> 6;
    const int n0   = blockIdx.x * 4;

    for (int i = tid; i < 4704; i += 256) {
        int img = i / 1176, rem = i % 1176;
        int c = rem / 196, rr = rem % 196;
        int y = rr / 14, xx = rr % 14;
        simg[img * 1260 + c * 210 + y * 15 + xx] = p1[(size_t)(n0 + img) * 1176 + rem];
    }
    for (int p = tid; p < 320; p += 256) {
        int ks = p >> 6, l = p & 63;
        int nn = l & 15, g = l >> 4;
        #pragma unroll
        for (int j = 0; j < 8; ++j) {
            int k = ks * 32 + g * 8 + j;
            float wv_ = (k < 150) ? w[nn * 150 + k] : 0.f;
            sB[p * 8 + j] = splitpack(wv_);
        }
    }
    if (tid < 16) sb[tid] = b[tid];
    __syncthreads();

    const int qw = (lane & 15) >> 2;
    const int dy = (lane >> 1) & 1, dx = lane & 1;
    const int g  = lane >> 4;
    int offs[40];
    #pragma unroll
    for (int ks = 0; ks < 5; ++ks)
        #pragma unroll
        for (int j = 0; j < 8; ++j) {
            int k = ks * 32 + g * 8 + j;
            int o = 0;
            if (k < 150) { int ci = k / 25, r = k % 25; o = ci * 210 + (r / 5) * 15 + (r % 5); }
            offs[ks * 8 + j] = o;
        }
    half8 bh[5], bl[5];
    #pragma unroll
    for (int ks = 0; ks < 5; ++ks)
        #pragma unroll
        for (int j = 0; j < 8; ++j) {
            uint u = sB[(ks * 64 + lane) * 8 + j];
            bh[ks][j] = lo16h(u); bl[ks][j] = hi16h(u);
        }

    const uint* img = simg + wv * 1260;
    const int n  = n0 + wv;
    const int cc = lane & 15;
    const int qr = lane >> 4;
    const float bias = sb[cc];
    float* outb = p2 + (size_t)n * 400 + cc * 25;

    for (int t = 0; t < 7; ++t) {
        int qa = t * 4 + qw; if (qa > 24) qa = 24;
        int qy = qa / 5, qx = qa % 5;
        int base = (2 * qy + dy) * 15 + (2 * qx + dx);
        f32x4 acc = {0.f, 0.f, 0.f, 0.f};
        #pragma unroll
        for (int ks = 0; ks < 5; ++ks) {
            uint up[8];
            #pragma unroll
            for (int j = 0; j < 8; ++j) up[j] = img[base + offs[ks * 8 + j]];
            half8 ah, al;
            #pragma unroll
            for (int j = 0; j < 8; ++j) { ah[j] = lo16h(up[j]); al[j] = hi16h(up[j]); }
            acc = __builtin_amdgcn_mfma_f32_16x16x32_f16(al, bl[ks], acc, 0, 0, 0);
            acc = __builtin_amdgcn_mfma_f32_16x16x32_f16(al, bh[ks], acc, 0, 0, 0);
            acc = __builtin_amdgcn_mfma_f32_16x16x32_f16(ah, bl[ks], acc, 0, 0, 0);
            acc = __builtin_amdgcn_mfma_f32_16x16x32_f16(ah, bh[ks], acc, 0, 0, 0);
        }
        int qc = t * 4 + qr;
        if (qc < 25) {
            float m = fmaxf(fmaxf(acc[0], acc[1]), fmaxf(acc[2], acc[3]));
            outb[qc] = fmaxf(m + bias, 0.f);
        }
    }
}

// ---------------- fc1: [N,400] @ [120,400]^T + relu -> h1:[N,120] ----------------
__global__ __launch_bounds__(256) void k_fc1(const float* __restrict__ p2,
                                             const float* __restrict__ w,
                                             const float* __restrict__ b,
                                             float* __restrict__ h1) {
    __shared__ float sa[64 * 100];
    __shared__ float swt[120 * 101];
    const int tid = threadIdx.x;
    const int n0 = blockIdx.x * 64;
    const int tc = tid % 30, tr = tid / 30;
    float acc[8][4];
    #pragma unroll
    for (int i = 0; i < 8; ++i)
        #pragma unroll
        for (int j = 0; j < 4; ++j) acc[i][j] = 0.f;

    for (int kt = 0; kt < 4; ++kt) {
        __syncthreads();
        for (int i = tid; i < 1600; i += 256) {
            int r = i / 25, k4 = (i % 25) * 4;
            float4 v = *(const float4*)(p2 + (size_t)(n0 + r) * 400 + kt * 100 + k4);
            *(float4*)(sa + r * 100 + k4) = v;
        }
        for (int i = tid; i < 3000; i += 256) {
            int c = i / 25, k4 = (i % 25) * 4;
            float4 v = *(const float4*)(w + (size_t)c * 400 + kt * 100 + k4);
            float* d = swt + c * 101 + k4;
            d[0] = v.x; d[1] = v.y; d[2] = v.z; d[3] = v.w;
        }
        __syncthreads();
        if (tr < 8) {
            #pragma unroll 4
            for (int k = 0; k < 100; ++k) {
                float av[8], wv[4];
                #pragma unroll
                for (int i = 0; i < 8; ++i) av[i] = sa[(tr * 8 + i) * 100 + k];
                #pragma unroll
                for (int j = 0; j < 4; ++j) wv[j] = swt[(tc * 4 + j) * 101 + k];
                #pragma unroll
                for (int i = 0; i < 8; ++i)
                    #pragma unroll
                    for (int j = 0; j < 4; ++j) acc[i][j] = fmaf(av[i], wv[j], acc[i][j]);
            }
        }
    }
    if (tr < 8) {
        #pragma unroll
        for (int j = 0; j < 4; ++j) {
            const int o = tc * 4 + j;
            const float bo = b[o];
            #pragma unroll
            for (int i = 0; i < 8; ++i) {
                const int rr = n0 + tr * 8 + i;
                h1[(size_t)rr * 120 + o] = fmaxf(acc[i][j] + bo, 0.f);
            }
        }
    }
}

// ---------------- compose: C[e][o][d] = sum_j head_w[o][j]*expert_w[e][j][d] ----------------
__global__ __launch_bounds__(256) void k_compose(const float* __restrict__ ew,
                                                 const float* __restrict__ eb,
                                                 const float* __restrict__ hw,
                                                 float* __restrict__ C,
                                                 float* __restrict__ hb2) {
    __shared__ float shw[840];
    __shared__ float seb[672];
    const int e = blockIdx.x, tid = threadIdx.x;
    for (int i = tid; i < 840; i += 256) shw[i] = hw[i];
    for (int i = tid; i < 672; i += 256) seb[i] = eb[i];
    __syncthreads();
    for (int i = tid; i < 840; i += 256) {
        int o = i / 84, d = i % 84;
        float s = 0.f;
        for (int j = 0; j < 84; ++j)
            s = fmaf(shw[o * 84 + j], ew[((size_t)e * 84 + j) * 84 + d], s);
        C[e * 840 + i] = s;
    }
    if (tid < 10) {
        float s = 0.f;
        for (int j = 0; j < 84; ++j) s = fmaf(shw[tid * 84 + j], seb[e * 84 + j], s);
        hb2[e * 10 + tid] = s;
    }
}

// ---------------- tail: fc2+relu, gate, top2-softmax, MoE(composed)+head ----------------
__global__ __launch_bounds__(256) void k_tail(const float* __restrict__ h1,
                                              const float* __restrict__ f2w,
                                              const float* __restrict__ f2b,
                                              const float* __restrict__ gw,
                                              const float* __restrict__ Cw,
                                              const float* __restrict__ hb2,
                                              const float* __restrict__ headb,
                                              float* __restrict__ out) {
    __shared__ float sh1[64 * 120];
    __shared__ float sfw[84 * 121];
    __shared__ float sfb[84];
    __shared__ float sgw[672];
    __shared__ float sh[64 * 85];
    __shared__ float sC[6800];
    __shared__ float shb2[80];
    __shared__ float shb[10];
    __shared__ float slog[64 * 9];
    __shared__ float swt[128];
    __shared__ int   sei[128];
    const int tid = threadIdx.x;
    const int n0 = blockIdx.x * 64;

    {
        const float4* g = (const float4*)(h1 + (size_t)n0 * 120);
        float4* s = (float4*)sh1;
        for (int i = tid; i < 1920; i += 256) s[i] = g[i];
    }
    for (int i = tid; i < 2520; i += 256) {
        int o = i / 30, k4 = (i % 30) * 4;
        float4 v = *(const float4*)(f2w + (size_t)o * 120 + k4);
        float* d = sfw + o * 121 + k4;
        d[0] = v.x; d[1] = v.y; d[2] = v.z; d[3] = v.w;
    }
    for (int i = tid; i < 6720; i += 256) sC[(i / 84) * 85 + (i % 84)] = Cw[i];
    for (int i = tid; i < 672; i += 256) sgw[i] = gw[i];
    if (tid < 84) sfb[tid] = f2b[tid];
    if (tid < 80) shb2[tid] = hb2[tid];
    if (tid < 10) shb[tid] = headb[tid];
    __syncthreads();

    for (int i = tid; i < 5376; i += 256) {
        const int t = i / 84, o = i % 84;
        const float* a = sh1 + t * 120;
        const float* wr = sfw + o * 121;
        float s = 0.f;
        #pragma unroll 8
        for (int k = 0; k < 120; ++k) s = fmaf(a[k], wr[k], s);
        sh[t * 85 + o] = fmaxf(s + sfb[o], 0.f);
    }
    __syncthreads();

    for (int i = tid; i < 512; i += 256) {
        const int t = i / 8, e = i % 8;
        const float* a = sh + t * 85;
        float s = 0.f;
        #pragma unroll 4
        for (int d = 0; d < 84; ++d) s = fmaf(a[d], sgw[d * 8 + e], s);
        slog[t * 9 + e] = s;
    }
    __syncthreads();

    if (tid < 64) {
        const float* l = slog + tid * 9;
        float m1 = l[0]; int i1 = 0;
        #pragma unroll
        for (int e = 1; e < 8; ++e) if (l[e] > m1) { m1 = l[e]; i1 = e; }
        float m2 = -1e30f; int i2 = 0;
        #pragma unroll
        for (int e = 0; e < 8; ++e) if (e != i1 && l[e] > m2) { m2 = l[e]; i2 = e; }
        const float r = expf(m2 - m1);
        const float inv = 1.f / (1.f + r);
        swt[tid * 2] = inv; swt[tid * 2 + 1] = r * inv;
        sei[tid * 2] = i1; sei[tid * 2 + 1] = i2;
    }
    __syncthreads();

    for (int i = tid; i < 640; i += 256) {
        const int t = i / 10, o = i % 10;
        const float* a = sh + t * 85;
        const float w0 = swt[t * 2], w1 = swt[t * 2 + 1];
        const int e0 = sei[t * 2], e1 = sei[t * 2 + 1];
        const float* c0 = sC + (e0 * 10 + o) * 85;
        const float* c1 = sC + (e1 * 10 + o) * 85;
        float s0 = 0.f, s1 = 0.f;
        #pragma unroll 4
        for (int d = 0; d < 84; ++d) {
            s0 = fmaf(a[d], c0[d], s0);
            s1 = fmaf(a[d], c1[d], s1);
        }
        out[(size_t)(n0 + t) * 10 + o] =
            shb[o] + w0 * (s0 + shb2[e0 * 10 + o]) + w1 * (s1 + shb2[e1 * 10 + o]);
    }
}

extern "C" void kernel_launch(void* const* d_in, const int* in_sizes, int n_in,
                              void* d_out, int out_size, void* d_ws, size_t ws_size,
                              hipStream_t stream) {
    const float* x   = (const float*)d_in[0];
    const float* c1w = (const float*)d_in[1];
    const float* c1b = (const float*)d_in[2];
    const float* c2w = (const float*)d_in[3];
    const float* c2b = (const float*)d_in[4];
    const float* f1w = (const float*)d_in[5];
    const float* f1b = (const float*)d_in[6];
    const float* f2w = (const float*)d_in[7];
    const float* f2b = (const float*)d_in[8];
    const float* gw  = (const float*)d_in[9];
    const float* ew  = (const float*)d_in[10];
    const float* eb  = (const float*)d_in[11];
    const float* hw  = (const float*)d_in[12];
    const float* hb  = (const float*)d_in[13];
    float* out = (float*)d_out;

    const int N = in_sizes[0] / 3072;   // 16384

    float* ws = (float*)d_ws;
    uint*  p1  = (uint*)ws;                    // N*1176 uints (packed hi/lo)
    float* p2  = ws + (size_t)N * 1176;        // N*400
    float* h1  = p2 + (size_t)N * 400;         // N*120
    float* C   = h1 + (size_t)N * 120;         // 6720
    float* hb2 = C + 6720;                     // 80

    k_conv1<<<N / 4, 256, 0, stream>>>(x, c1w, c1b, p1);
    k_conv2<<<N / 4, 256, 0, stream>>>(p1, c2w, c2b, p2);
    k_fc1<<<N / 64, 256, 0, stream>>>(p2, f1w, f1b, h1);
    k_compose<<<8, 256, 0, stream>>>(ew, eb, hw, C, hb2);
    k_tail<<<N / 64, 256, 0, stream>>>(h1, f2w, f2b, gw, C, hb2, hb, out);
}

// Round 6
// 376.956 us; speedup vs baseline: 2.0558x; 1.1085x over previous
//
#include <hip/hip_runtime.h>
#include <math.h>

typedef _Float16 half8 __attribute__((ext_vector_type(8)));
typedef float f32x4 __attribute__((ext_vector_type(4)));

// split fp32 -> (hi,lo) fp16 pair packed in one uint (hi in low 16, lo in high 16)
__device__ inline uint splitpack(float v) {
    _Float16 h = (_Float16)v;
    float r = v - (float)h;
    _Float16 l = (_Float16)r;
    return (uint)__builtin_bit_cast(unsigned short, h) |
           ((uint)__builtin_bit_cast(unsigned short, l) << 16);
}
__device__ inline _Float16 lo16h(uint u) { return __builtin_bit_cast(_Float16, (unsigned short)(u & 0xffffu)); }
__device__ inline _Float16 hi16h(uint u) { return __builtin_bit_cast(_Float16, (unsigned short)(u >> 16)); }

// ---------------- conv1 via split-fp16 MFMA, dx-in-N, pair-aligned b64 reads ----------------
// x:[N,3,32,32] -> p1:[N,6,14,14] packed uint.
// Per image GEMM: M = 392 (r = qx*28 + y), N cols = dx*8 + c (12/16), K = 90 pad 96.
// K-slot permutation: phys pair P = ks*16 + g*4 + pi  ->  (rho = P/3, pairi = P%3),
// ci = rho/5, ky = rho%5, kxp = pairi*2 + (j&1).  All pair addresses even -> ds_read_b64.
// LDS image: [ci][32][34] per image (strides 1088/34, all even).
__global__ __launch_bounds__(256) void k_conv1(const float* __restrict__ x,
                                               const float* __restrict__ w,
                                               const float* __restrict__ b,
                                               uint* __restrict__ p1, int n_total) {
    __shared__ uint simg[9808];           // 3 imgs * 3264 + pad, 39.2 KB
    __shared__ uint sB[3 * 64 * 8];       // 6 KB
    __shared__ float sb[6];
    const int tid  = threadIdx.x;
    const int lane = tid & 63;
    const int wv   = tid >> 6;
    const int n0   = blockIdx.x * 3;
    const int nimg = min(3, n_total - n0);

    // stage images fp32 -> packed split-fp16, stride-34 rows
    for (int im = 0; im < nimg; ++im) {
        for (int i = tid; i < 768; i += 256) {
            int plane = i >> 8, rr = (i & 255) >> 3, c4 = (i & 7) << 2;
            float4 v = *(const float4*)(x + ((size_t)(n0 + im) * 3 + plane) * 1024 + rr * 32 + c4);
            uint* d = simg + im * 3264 + plane * 1088 + rr * 34 + c4;
            d[0] = splitpack(v.x); d[1] = splitpack(v.y);
            d[2] = splitpack(v.z); d[3] = splitpack(v.w);
        }
    }
    // B fragments under the pair permutation
    for (int p = tid; p < 192; p += 256) {
        int ks = p >> 6, l = p & 63;
        int colb = l & 15, g = l >> 4;
        int c = colb & 7, dx = colb >> 3;
        #pragma unroll
        for (int j = 0; j < 8; ++j) {
            int P = ks * 16 + g * 4 + (j >> 1);
            float val = 0.f;
            if (P < 45 && c < 6) {
                int rho = P / 3, pairi = P % 3;
                int ci = rho / 5, ky = rho % 5, kxp = pairi * 2 + (j & 1);
                int kx = kxp - dx;
                if (kx >= 0 && kx < 5) val = w[c * 75 + ci * 25 + ky * 5 + kx];
            }
            sB[p * 8 + j] = splitpack(val);
        }
    }
    if (tid < 6) sb[tid] = b[tid];
    __syncthreads();

    const int g = lane >> 4;
    int poff[12];                          // even pair offsets (uints)
    #pragma unroll
    for (int i = 0; i < 12; ++i) {
        int ks = i >> 2, pi = i & 3;
        int P = ks * 16 + g * 4 + pi;
        int o = 0;
        if (P < 45) {
            int rho = P / 3, pairi = P % 3;
            o = (rho / 5) * 1088 + (rho % 5) * 34 + pairi * 2;
        }
        poff[i] = o;
    }
    half8 bh[3], bl[3];
    #pragma unroll
    for (int ks = 0; ks < 3; ++ks)
        #pragma unroll
        for (int j = 0; j < 8; ++j) {
            uint u = sB[(ks * 64 + lane) * 8 + j];
            bh[ks][j] = lo16h(u); bl[ks][j] = hi16h(u);
        }

    const int colb = lane & 15;
    const int c  = colb & 7, dx = colb >> 3;
    const int qr = lane >> 4;
    const float bias = (c < 6) ? sb[c] : 0.f;

    for (int t = wv; t < nimg * 25; t += 4) {
        int im = t / 25, tl = t - im * 25;
        const uint* img = simg + im * 3264;
        int r = tl * 16 + colb; if (r > 391) r = 391;
        int qx = r / 28, y = r - qx * 28;
        int base2 = y * 34 + 2 * qx;
        f32x4 acc = {0.f, 0.f, 0.f, 0.f};
        #pragma unroll
        for (int ks = 0; ks < 3; ++ks) {
            uint hu[4], lu[4];
            #pragma unroll
            for (int pi = 0; pi < 4; ++pi) {
                const uint* ap = img + base2 + poff[ks * 4 + pi];
                uint2 v = *(const uint2*)__builtin_assume_aligned((const void*)ap, 8);
                hu[pi] = __builtin_amdgcn_perm(v.y, v.x, 0x05040100u);  // hi parts
                lu[pi] = __builtin_amdgcn_perm(v.y, v.x, 0x07060302u);  // lo parts
            }
            uint4 hv; hv.x = hu[0]; hv.y = hu[1]; hv.z = hu[2]; hv.w = hu[3];
            uint4 lv; lv.x = lu[0]; lv.y = lu[1]; lv.z = lu[2]; lv.w = lu[3];
            half8 ah = __builtin_bit_cast(half8, hv);
            half8 al = __builtin_bit_cast(half8, lv);
            acc = __builtin_amdgcn_mfma_f32_16x16x32_f16(ah, bh[ks], acc, 0, 0, 0);
            acc = __builtin_amdgcn_mfma_f32_16x16x32_f16(ah, bl[ks], acc, 0, 0, 0);
            acc = __builtin_amdgcn_mfma_f32_16x16x32_f16(al, bh[ks], acc, 0, 0, 0);
        }
        float m01 = fmaxf(acc[0], acc[1]);
        float m23 = fmaxf(acc[2], acc[3]);
        float p01 = fmaxf(m01, __shfl_xor(m01, 8, 64));
        float p23 = fmaxf(m23, __shfl_xor(m23, 8, 64));
        if (dx == 0 && c < 6) {
            uint* outb = p1 + ((size_t)(n0 + im) * 6 + c) * 196;
            int r0 = tl * 16 + qr * 4;
            if (r0 + 1 < 392) {
                int qx0 = r0 / 28, y0 = r0 - qx0 * 28;
                outb[(y0 >> 1) * 14 + qx0] = splitpack(fmaxf(p01 + bias, 0.f));
            }
            int r2 = r0 + 2;
            if (r2 + 1 < 392) {
                int qx2 = r2 / 28, y2 = r2 - qx2 * 28;
                outb[(y2 >> 1) * 14 + qx2] = splitpack(fmaxf(p23 + bias, 0.f));
            }
        }
    }
}

// ---------------- conv2 via split-fp16 MFMA: p1 packed -> p2:[N,400] fp32 ----------------
__global__ __launch_bounds__(256) void k_conv2(const uint* __restrict__ p1,
                                               const float* __restrict__ w,
                                               const float* __restrict__ b,
                                               float* __restrict__ p2) {
    __shared__ uint simg[4 * 1260];
    __shared__ uint sB[5 * 64 * 8];
    __shared__ float sb[16];
    const int tid  = threadIdx.x;
    const int lane = tid & 63;
    const int wv   = tid >> 6;
    const int n0   = blockIdx.x * 4;

    for (int i = tid; i < 4704; i += 256) {
        int img = i / 1176, rem = i % 1176;
        int c = rem / 196, rr = rem % 196;
        int y = rr / 14, xx = rr % 14;
        simg[img * 1260 + c * 210 + y * 15 + xx] = p1[(size_t)(n0 + img) * 1176 + rem];
    }
    for (int p = tid; p < 320; p += 256) {
        int ks = p >> 6, l = p & 63;
        int nn = l & 15, g = l >> 4;
        #pragma unroll
        for (int j = 0; j < 8; ++j) {
            int k = ks * 32 + g * 8 + j;
            float wv_ = (k < 150) ? w[nn * 150 + k] : 0.f;
            sB[p * 8 + j] = splitpack(wv_);
        }
    }
    if (tid < 16) sb[tid] = b[tid];
    __syncthreads();

    const int qw = (lane & 15) >> 2;
    const int dy = (lane >> 1) & 1, dx = lane & 1;
    const int g  = lane >> 4;
    int offs[40];
    #pragma unroll
    for (int ks = 0; ks < 5; ++ks)
        #pragma unroll
        for (int j = 0; j < 8; ++j) {
            int k = ks * 32 + g * 8 + j;
            int o = 0;
            if (k < 150) { int ci = k / 25, r = k % 25; o = ci * 210 + (r / 5) * 15 + (r % 5); }
            offs[ks * 8 + j] = o;
        }
    half8 bh[5], bl[5];
    #pragma unroll
    for (int ks = 0; ks < 5; ++ks)
        #pragma unroll
        for (int j = 0; j < 8; ++j) {
            uint u = sB[(ks * 64 + lane) * 8 + j];
            bh[ks][j] = lo16h(u); bl[ks][j] = hi16h(u);
        }

    const uint* img = simg + wv * 1260;
    const int n  = n0 + wv;
    const int cc = lane & 15;
    const int qr = lane >> 4;
    const float bias = sb[cc];
    float* outb = p2 + (size_t)n * 400 + cc * 25;

    for (int t = 0; t < 7; ++t) {
        int qa = t * 4 + qw; if (qa > 24) qa = 24;
        int qy = qa / 5, qx = qa % 5;
        int base = (2 * qy + dy) * 15 + (2 * qx + dx);
        f32x4 acc = {0.f, 0.f, 0.f, 0.f};
        #pragma unroll
        for (int ks = 0; ks < 5; ++ks) {
            uint up[8];
            #pragma unroll
            for (int j = 0; j < 8; ++j) up[j] = img[base + offs[ks * 8 + j]];
            half8 ah, al;
            #pragma unroll
            for (int j = 0; j < 8; ++j) { ah[j] = lo16h(up[j]); al[j] = hi16h(up[j]); }
            acc = __builtin_amdgcn_mfma_f32_16x16x32_f16(ah, bh[ks], acc, 0, 0, 0);
            acc = __builtin_amdgcn_mfma_f32_16x16x32_f16(ah, bl[ks], acc, 0, 0, 0);
            acc = __builtin_amdgcn_mfma_f32_16x16x32_f16(al, bh[ks], acc, 0, 0, 0);
        }
        int qc = t * 4 + qr;
        if (qc < 25) {
            float m = fmaxf(fmaxf(acc[0], acc[1]), fmaxf(acc[2], acc[3]));
            outb[qc] = fmaxf(m + bias, 0.f);
        }
    }
}

// ---------------- fc1: [N,400] @ [120,400]^T + relu -> h1:[N,120] ----------------
__global__ __launch_bounds__(256) void k_fc1(const float* __restrict__ p2,
                                             const float* __restrict__ w,
                                             const float* __restrict__ b,
                                             float* __restrict__ h1) {
    __shared__ float sa[64 * 100];
    __shared__ float swt[120 * 101];
    const int tid = threadIdx.x;
    const int n0 = blockIdx.x * 64;
    const int tc = tid % 30, tr = tid / 30;
    float acc[8][4];
    #pragma unroll
    for (int i = 0; i < 8; ++i)
        #pragma unroll
        for (int j = 0; j < 4; ++j) acc[i][j] = 0.f;

    for (int kt = 0; kt < 4; ++kt) {
        __syncthreads();
        for (int i = tid; i < 1600; i += 256) {
            int r = i / 25, k4 = (i % 25) * 4;
            float4 v = *(const float4*)(p2 + (size_t)(n0 + r) * 400 + kt * 100 + k4);
            *(float4*)(sa + r * 100 + k4) = v;
        }
        for (int i = tid; i < 3000; i += 256) {
            int c = i / 25, k4 = (i % 25) * 4;
            float4 v = *(const float4*)(w + (size_t)c * 400 + kt * 100 + k4);
            float* d = swt + c * 101 + k4;
            d[0] = v.x; d[1] = v.y; d[2] = v.z; d[3] = v.w;
        }
        __syncthreads();
        if (tr < 8) {
            #pragma unroll 4
            for (int k = 0; k < 100; ++k) {
                float av[8], wv[4];
                #pragma unroll
                for (int i = 0; i < 8; ++i) av[i] = sa[(tr * 8 + i) * 100 + k];
                #pragma unroll
                for (int j = 0; j < 4; ++j) wv[j] = swt[(tc * 4 + j) * 101 + k];
                #pragma unroll
                for (int i = 0; i < 8; ++i)
                    #pragma unroll
                    for (int j = 0; j < 4; ++j) acc[i][j] = fmaf(av[i], wv[j], acc[i][j]);
            }
        }
    }
    if (tr < 8) {
        #pragma unroll
        for (int j = 0; j < 4; ++j) {
            const int o = tc * 4 + j;
            const float bo = b[o];
            #pragma unroll
            for (int i = 0; i < 8; ++i) {
                const int rr = n0 + tr * 8 + i;
                h1[(size_t)rr * 120 + o] = fmaxf(acc[i][j] + bo, 0.f);
            }
        }
    }
}

// ---------------- compose: C[e][o][d] = sum_j head_w[o][j]*expert_w[e][j][d] ----------------
__global__ __launch_bounds__(256) void k_compose(const float* __restrict__ ew,
                                                 const float* __restrict__ eb,
                                                 const float* __restrict__ hw,
                                                 float* __restrict__ C,
                                                 float* __restrict__ hb2) {
    __shared__ float shw[840];
    __shared__ float seb[672];
    const int e = blockIdx.x, tid = threadIdx.x;
    for (int i = tid; i < 840; i += 256) shw[i] = hw[i];
    for (int i = tid; i < 672; i += 256) seb[i] = eb[i];
    __syncthreads();
    for (int i = tid; i < 840; i += 256) {
        int o = i / 84, d = i % 84;
        float s = 0.f;
        for (int j = 0; j < 84; ++j)
            s = fmaf(shw[o * 84 + j], ew[((size_t)e * 84 + j) * 84 + d], s);
        C[e * 840 + i] = s;
    }
    if (tid < 10) {
        float s = 0.f;
        for (int j = 0; j < 84; ++j) s = fmaf(shw[tid * 84 + j], seb[e * 84 + j], s);
        hb2[e * 10 + tid] = s;
    }
}

// ---------------- tail: fc2+relu, gate, top2-softmax, MoE(composed)+head ----------------
__global__ __launch_bounds__(256) void k_tail(const float* __restrict__ h1,
                                              const float* __restrict__ f2w,
                                              const float* __restrict__ f2b,
                                              const float* __restrict__ gw,
                                              const float* __restrict__ Cw,
                                              const float* __restrict__ hb2,
                                              const float* __restrict__ headb,
                                              float* __restrict__ out) {
    __shared__ float sh1[64 * 120];
    __shared__ float sfw[84 * 121];
    __shared__ float sfb[84];
    __shared__ float sgw[672];
    __shared__ float sh[64 * 85];
    __shared__ float sC[6800];
    __shared__ float shb2[80];
    __shared__ float shb[10];
    __shared__ float slog[64 * 9];
    __shared__ float swt[128];
    __shared__ int   sei[128];
    const int tid = threadIdx.x;
    const int n0 = blockIdx.x * 64;

    {
        const float4* g = (const float4*)(h1 + (size_t)n0 * 120);
        float4* s = (float4*)sh1;
        for (int i = tid; i < 1920; i += 256) s[i] = g[i];
    }
    for (int i = tid; i < 2520; i += 256) {
        int o = i / 30, k4 = (i % 30) * 4;
        float4 v = *(const float4*)(f2w + (size_t)o * 120 + k4);
        float* d = sfw + o * 121 + k4;
        d[0] = v.x; d[1] = v.y; d[2] = v.z; d[3] = v.w;
    }
    for (int i = tid; i < 6720; i += 256) sC[(i / 84) * 85 + (i % 84)] = Cw[i];
    for (int i = tid; i < 672; i += 256) sgw[i] = gw[i];
    if (tid < 84) sfb[tid] = f2b[tid];
    if (tid < 80) shb2[tid] = hb2[tid];
    if (tid < 10) shb[tid] = headb[tid];
    __syncthreads();

    for (int i = tid; i < 5376; i += 256) {
        const int t = i / 84, o = i % 84;
        const float* a = sh1 + t * 120;
        const float* wr = sfw + o * 121;
        float s = 0.f;
        #pragma unroll 8
        for (int k = 0; k < 120; ++k) s = fmaf(a[k], wr[k], s);
        sh[t * 85 + o] = fmaxf(s + sfb[o], 0.f);
    }
    __syncthreads();

    for (int i = tid; i < 512; i += 256) {
        const int t = i / 8, e = i % 8;
        const float* a = sh + t * 85;
        float s = 0.f;
        #pragma unroll 4
        for (int d = 0; d < 84; ++d) s = fmaf(a[d], sgw[d * 8 + e], s);
        slog[t * 9 + e] = s;
    }
    __syncthreads();

    if (tid < 64) {
        const float* l = slog + tid * 9;
        float m1 = l[0]; int i1 = 0;
        #pragma unroll
        for (int e = 1; e < 8; ++e) if (l[e] > m1) { m1 = l[e]; i1 = e; }
        float m2 = -1e30f; int i2 = 0;
        #pragma unroll
        for (int e = 0; e < 8; ++e) if (e != i1 && l[e] > m2) { m2 = l[e]; i2 = e; }
        const float r = expf(m2 - m1);
        const float inv = 1.f / (1.f + r);
        swt[tid * 2] = inv; swt[tid * 2 + 1] = r * inv;
        sei[tid * 2] = i1; sei[tid * 2 + 1] = i2;
    }
    __syncthreads();

    for (int i = tid; i < 640; i += 256) {
        const int t = i / 10, o = i % 10;
        const float* a = sh + t * 85;
        const float w0 = swt[t * 2], w1 = swt[t * 2 + 1];
        const int e0 = sei[t * 2], e1 = sei[t * 2 + 1];
        const float* c0 = sC + (e0 * 10 + o) * 85;
        const float* c1 = sC + (e1 * 10 + o) * 85;
        float s0 = 0.f, s1 = 0.f;
        #pragma unroll 4
        for (int d = 0; d < 84; ++d) {
            s0 = fmaf(a[d], c0[d], s0);
            s1 = fmaf(a[d], c1[d], s1);
        }
        out[(size_t)(n0 + t) * 10 + o] =
            shb[o] + w0 * (s0 + shb2[e0 * 10 + o]) + w1 * (s1 + shb2[e1 * 10 + o]);
    }
}

extern "C" void kernel_launch(void* const* d_in, const int* in_sizes, int n_in,
                              void* d_out, int out_size, void* d_ws, size_t ws_size,
                              hipStream_t stream) {
    const float* x   = (const float*)d_in[0];
    const float* c1w = (const float*)d_in[1];
    const float* c1b = (const float*)d_in[2];
    const float* c2w = (const float*)d_in[3];
    const float* c2b = (const float*)d_in[4];
    const float* f1w = (const float*)d_in[5];
    const float* f1b = (const float*)d_in[6];
    const float* f2w = (const float*)d_in[7];
    const float* f2b = (const float*)d_in[8];
    const float* gw  = (const float*)d_in[9];
    const float* ew  = (const float*)d_in[10];
    const float* eb  = (const float*)d_in[11];
    const float* hw  = (const float*)d_in[12];
    const float* hb  = (const float*)d_in[13];
    float* out = (float*)d_out;

    const int N = in_sizes[0] / 3072;   // 16384

    float* ws = (float*)d_ws;
    uint*  p1  = (uint*)ws;                    // N*1176 uints (packed hi/lo)
    float* p2  = ws + (size_t)N * 1176;        // N*400
    float* h1  = p2 + (size_t)N * 400;         // N*120
    float* C   = h1 + (size_t)N * 120;         // 6720
    float* hb2 = C + 6720;                     // 80

    k_conv1<<<(N + 2) / 3, 256, 0, stream>>>(x, c1w, c1b, p1, N);
    k_conv2<<<N / 4, 256, 0, stream>>>(p1, c2w, c2b, p2);
    k_fc1<<<N / 64, 256, 0, stream>>>(p2, f1w, f1b, h1);
    k_compose<<<8, 256, 0, stream>>>(ew, eb, hw, C, hb2);
    k_tail<<<N / 64, 256, 0, stream>>>(h1, f2w, f2b, gw, C, hb2, hb, out);
}

// Round 7
// 369.520 us; speedup vs baseline: 2.0972x; 1.0201x over previous
//
#include <hip/hip_runtime.h>
#include <math.h>

typedef _Float16 half8 __attribute__((ext_vector_type(8)));
typedef float f32x4 __attribute__((ext_vector_type(4)));

// split fp32 -> (hi,lo) fp16 pair packed in one uint (hi in low 16, lo in high 16)
__device__ inline uint splitpack(float v) {
    _Float16 h = (_Float16)v;
    float r = v - (float)h;
    _Float16 l = (_Float16)r;
    return (uint)__builtin_bit_cast(unsigned short, h) |
           ((uint)__builtin_bit_cast(unsigned short, l) << 16);
}
__device__ inline _Float16 lo16h(uint u) { return __builtin_bit_cast(_Float16, (unsigned short)(u & 0xffffu)); }
__device__ inline _Float16 hi16h(uint u) { return __builtin_bit_cast(_Float16, (unsigned short)(u >> 16)); }

// ---------------- conv1 via split-fp16 MFMA, dx-in-N, pair-aligned b64 reads ----------------
// x:[N,3,32,32] -> p1:[N,6,14,14] packed uint.
// Per image GEMM: M = 392 (r = qx*28 + y), N cols = dx*8 + c (12/16), K = 90 pad 96.
// K-slot permutation: phys pair P = ks*16 + g*4 + pi  ->  (rho = P/3, pairi = P%3),
// ci = rho/5, ky = rho%5, kxp = pairi*2 + (j&1).  All pair addresses even -> ds_read_b64.
// LDS image: [ci][32][34] per image (strides 1088/34, all even).
// 2 imgs/block (32.2 KB LDS -> 4 blocks/CU) + dual accumulators (chain 9 -> 5).
__global__ __launch_bounds__(256) void k_conv1(const float* __restrict__ x,
                                               const float* __restrict__ w,
                                               const float* __restrict__ b,
                                               uint* __restrict__ p1) {
    __shared__ uint simg[6528];           // 2 imgs * 3264, 26.1 KB
    __shared__ uint sB[3 * 64 * 8];       // 6 KB
    __shared__ float sb[6];
    const int tid  = threadIdx.x;
    const int lane = tid & 63;
    const int wv   = tid >> 6;
    const int n0   = blockIdx.x * 2;

    // stage 2 images fp32 -> packed split-fp16, stride-34 rows
    for (int i = tid; i < 1536; i += 256) {
        int im = i >> 9 >> 1;              // i/768
        im = i / 768;
        int rem = i - im * 768;
        int plane = rem >> 8, rr = (rem & 255) >> 3, c4 = (rem & 7) << 2;
        float4 v = *(const float4*)(x + ((size_t)(n0 + im) * 3 + plane) * 1024 + rr * 32 + c4);
        uint* d = simg + im * 3264 + plane * 1088 + rr * 34 + c4;
        d[0] = splitpack(v.x); d[1] = splitpack(v.y);
        d[2] = splitpack(v.z); d[3] = splitpack(v.w);
    }
    // B fragments under the pair permutation
    for (int p = tid; p < 192; p += 256) {
        int ks = p >> 6, l = p & 63;
        int colb = l & 15, g = l >> 4;
        int c = colb & 7, dx = colb >> 3;
        #pragma unroll
        for (int j = 0; j < 8; ++j) {
            int P = ks * 16 + g * 4 + (j >> 1);
            float val = 0.f;
            if (P < 45 && c < 6) {
                int rho = P / 3, pairi = P % 3;
                int ci = rho / 5, ky = rho % 5, kxp = pairi * 2 + (j & 1);
                int kx = kxp - dx;
                if (kx >= 0 && kx < 5) val = w[c * 75 + ci * 25 + ky * 5 + kx];
            }
            sB[p * 8 + j] = splitpack(val);
        }
    }
    if (tid < 6) sb[tid] = b[tid];
    __syncthreads();

    const int g = lane >> 4;
    int poff[12];                          // even pair offsets (uints)
    #pragma unroll
    for (int i = 0; i < 12; ++i) {
        int ks = i >> 2, pi = i & 3;
        int P = ks * 16 + g * 4 + pi;
        int o = 0;
        if (P < 45) {
            int rho = P / 3, pairi = P % 3;
            o = (rho / 5) * 1088 + (rho % 5) * 34 + pairi * 2;
        }
        poff[i] = o;
    }
    half8 bh[3], bl[3];
    #pragma unroll
    for (int ks = 0; ks < 3; ++ks)
        #pragma unroll
        for (int j = 0; j < 8; ++j) {
            uint u = sB[(ks * 64 + lane) * 8 + j];
            bh[ks][j] = lo16h(u); bl[ks][j] = hi16h(u);
        }

    const int colb = lane & 15;
    const int c  = colb & 7, dx = colb >> 3;
    const int qr = lane >> 4;
    const float bias = (c < 6) ? sb[c] : 0.f;

    for (int t = wv; t < 50; t += 4) {
        int im = (t >= 25) ? 1 : 0;
        int tl = t - im * 25;
        const uint* img = simg + im * 3264;
        int r = tl * 16 + colb; if (r > 391) r = 391;
        int qx = r / 28, y = r - qx * 28;
        int base2 = y * 34 + 2 * qx;
        f32x4 acc2[2] = {{0.f,0.f,0.f,0.f},{0.f,0.f,0.f,0.f}};
        int pp = 0;
        #pragma unroll
        for (int ks = 0; ks < 3; ++ks) {
            uint hu[4], lu[4];
            #pragma unroll
            for (int pi = 0; pi < 4; ++pi) {
                const uint* ap = img + base2 + poff[ks * 4 + pi];
                uint2 v = *(const uint2*)__builtin_assume_aligned((const void*)ap, 8);
                hu[pi] = __builtin_amdgcn_perm(v.y, v.x, 0x05040100u);  // hi parts
                lu[pi] = __builtin_amdgcn_perm(v.y, v.x, 0x07060302u);  // lo parts
            }
            uint4 hv; hv.x = hu[0]; hv.y = hu[1]; hv.z = hu[2]; hv.w = hu[3];
            uint4 lv; lv.x = lu[0]; lv.y = lu[1]; lv.z = lu[2]; lv.w = lu[3];
            half8 ah = __builtin_bit_cast(half8, hv);
            half8 al = __builtin_bit_cast(half8, lv);
            acc2[pp & 1] = __builtin_amdgcn_mfma_f32_16x16x32_f16(ah, bh[ks], acc2[pp & 1], 0, 0, 0); ++pp;
            acc2[pp & 1] = __builtin_amdgcn_mfma_f32_16x16x32_f16(ah, bl[ks], acc2[pp & 1], 0, 0, 0); ++pp;
            acc2[pp & 1] = __builtin_amdgcn_mfma_f32_16x16x32_f16(al, bh[ks], acc2[pp & 1], 0, 0, 0); ++pp;
        }
        f32x4 acc;
        #pragma unroll
        for (int i = 0; i < 4; ++i) acc[i] = acc2[0][i] + acc2[1][i];

        float m01 = fmaxf(acc[0], acc[1]);
        float m23 = fmaxf(acc[2], acc[3]);
        float p01 = fmaxf(m01, __shfl_xor(m01, 8, 64));
        float p23 = fmaxf(m23, __shfl_xor(m23, 8, 64));
        if (dx == 0 && c < 6) {
            uint* outb = p1 + ((size_t)(n0 + im) * 6 + c) * 196;
            int r0 = tl * 16 + qr * 4;
            if (r0 + 1 < 392) {
                int qx0 = r0 / 28, y0 = r0 - qx0 * 28;
                outb[(y0 >> 1) * 14 + qx0] = splitpack(fmaxf(p01 + bias, 0.f));
            }
            int r2 = r0 + 2;
            if (r2 + 1 < 392) {
                int qx2 = r2 / 28, y2 = r2 - qx2 * 28;
                outb[(y2 >> 1) * 14 + qx2] = splitpack(fmaxf(p23 + bias, 0.f));
            }
        }
    }
}

// ---------------- conv2 via split-fp16 MFMA: p1 packed -> p2:[N,400] fp32 ----------------
__global__ __launch_bounds__(256) void k_conv2(const uint* __restrict__ p1,
                                               const float* __restrict__ w,
                                               const float* __restrict__ b,
                                               float* __restrict__ p2) {
    __shared__ uint simg[4 * 1260];
    __shared__ uint sB[5 * 64 * 8];
    __shared__ float sb[16];
    const int tid  = threadIdx.x;
    const int lane = tid & 63;
    const int wv   = tid >> 6;
    const int n0   = blockIdx.x * 4;

    for (int i = tid; i < 4704; i += 256) {
        int img = i / 1176, rem = i % 1176;
        int c = rem / 196, rr = rem % 196;
        int y = rr / 14, xx = rr % 14;
        simg[img * 1260 + c * 210 + y * 15 + xx] = p1[(size_t)(n0 + img) * 1176 + rem];
    }
    for (int p = tid; p < 320; p += 256) {
        int ks = p >> 6, l = p & 63;
        int nn = l & 15, g = l >> 4;
        #pragma unroll
        for (int j = 0; j < 8; ++j) {
            int k = ks * 32 + g * 8 + j;
            float wv_ = (k < 150) ? w[nn * 150 + k] : 0.f;
            sB[p * 8 + j] = splitpack(wv_);
        }
    }
    if (tid < 16) sb[tid] = b[tid];
    __syncthreads();

    const int qw = (lane & 15) >> 2;
    const int dy = (lane >> 1) & 1, dx = lane & 1;
    const int g  = lane >> 4;
    int offs[40];
    #pragma unroll
    for (int ks = 0; ks < 5; ++ks)
        #pragma unroll
        for (int j = 0; j < 8; ++j) {
            int k = ks * 32 + g * 8 + j;
            int o = 0;
            if (k < 150) { int ci = k / 25, r = k % 25; o = ci * 210 + (r / 5) * 15 + (r % 5); }
            offs[ks * 8 + j] = o;
        }
    half8 bh[5], bl[5];
    #pragma unroll
    for (int ks = 0; ks < 5; ++ks)
        #pragma unroll
        for (int j = 0; j < 8; ++j) {
            uint u = sB[(ks * 64 + lane) * 8 + j];
            bh[ks][j] = lo16h(u); bl[ks][j] = hi16h(u);
        }

    const uint* img = simg + wv * 1260;
    const int n  = n0 + wv;
    const int cc = lane & 15;
    const int qr = lane >> 4;
    const float bias = sb[cc];
    float* outb = p2 + (size_t)n * 400 + cc * 25;

    for (int t = 0; t < 7; ++t) {
        int qa = t * 4 + qw; if (qa > 24) qa = 24;
        int qy = qa / 5, qx = qa % 5;
        int base = (2 * qy + dy) * 15 + (2 * qx + dx);
        f32x4 acc = {0.f, 0.f, 0.f, 0.f};
        #pragma unroll
        for (int ks = 0; ks < 5; ++ks) {
            uint up[8];
            #pragma unroll
            for (int j = 0; j < 8; ++j) up[j] = img[base + offs[ks * 8 + j]];
            half8 ah, al;
            #pragma unroll
            for (int j = 0; j < 8; ++j) { ah[j] = lo16h(up[j]); al[j] = hi16h(up[j]); }
            acc = __builtin_amdgcn_mfma_f32_16x16x32_f16(ah, bh[ks], acc, 0, 0, 0);
            acc = __builtin_amdgcn_mfma_f32_16x16x32_f16(ah, bl[ks], acc, 0, 0, 0);
            acc = __builtin_amdgcn_mfma_f32_16x16x32_f16(al, bh[ks], acc, 0, 0, 0);
        }
        int qc = t * 4 + qr;
        if (qc < 25) {
            float m = fmaxf(fmaxf(acc[0], acc[1]), fmaxf(acc[2], acc[3]));
            outb[qc] = fmaxf(m + bias, 0.f);
        }
    }
}

// ---------------- fc1: [N,400] @ [120,400]^T + relu -> h1:[N,120] ----------------
__global__ __launch_bounds__(256) void k_fc1(const float* __restrict__ p2,
                                             const float* __restrict__ w,
                                             const float* __restrict__ b,
                                             float* __restrict__ h1) {
    __shared__ float sa[64 * 100];
    __shared__ float swt[120 * 101];
    const int tid = threadIdx.x;
    const int n0 = blockIdx.x * 64;
    const int tc = tid % 30, tr = tid / 30;
    float acc[8][4];
    #pragma unroll
    for (int i = 0; i < 8; ++i)
        #pragma unroll
        for (int j = 0; j < 4; ++j) acc[i][j] = 0.f;

    for (int kt = 0; kt < 4; ++kt) {
        __syncthreads();
        for (int i = tid; i < 1600; i += 256) {
            int r = i / 25, k4 = (i % 25) * 4;
            float4 v = *(const float4*)(p2 + (size_t)(n0 + r) * 400 + kt * 100 + k4);
            *(float4*)(sa + r * 100 + k4) = v;
        }
        for (int i = tid; i < 3000; i += 256) {
            int c = i / 25, k4 = (i % 25) * 4;
            float4 v = *(const float4*)(w + (size_t)c * 400 + kt * 100 + k4);
            float* d = swt + c * 101 + k4;
            d[0] = v.x; d[1] = v.y; d[2] = v.z; d[3] = v.w;
        }
        __syncthreads();
        if (tr < 8) {
            #pragma unroll 4
            for (int k = 0; k < 100; ++k) {
                float av[8], wv[4];
                #pragma unroll
                for (int i = 0; i < 8; ++i) av[i] = sa[(tr * 8 + i) * 100 + k];
                #pragma unroll
                for (int j = 0; j < 4; ++j) wv[j] = swt[(tc * 4 + j) * 101 + k];
                #pragma unroll
                for (int i = 0; i < 8; ++i)
                    #pragma unroll
                    for (int j = 0; j < 4; ++j) acc[i][j] = fmaf(av[i], wv[j], acc[i][j]);
            }
        }
    }
    if (tr < 8) {
        #pragma unroll
        for (int j = 0; j < 4; ++j) {
            const int o = tc * 4 + j;
            const float bo = b[o];
            #pragma unroll
            for (int i = 0; i < 8; ++i) {
                const int rr = n0 + tr * 8 + i;
                h1[(size_t)rr * 120 + o] = fmaxf(acc[i][j] + bo, 0.f);
            }
        }
    }
}

// ---------------- compose: C[e][o][d] = sum_j head_w[o][j]*expert_w[e][j][d] ----------------
__global__ __launch_bounds__(256) void k_compose(const float* __restrict__ ew,
                                                 const float* __restrict__ eb,
                                                 const float* __restrict__ hw,
                                                 float* __restrict__ C,
                                                 float* __restrict__ hb2) {
    __shared__ float shw[840];
    __shared__ float seb[672];
    const int e = blockIdx.x, tid = threadIdx.x;
    for (int i = tid; i < 840; i += 256) shw[i] = hw[i];
    for (int i = tid; i < 672; i += 256) seb[i] = eb[i];
    __syncthreads();
    for (int i = tid; i < 840; i += 256) {
        int o = i / 84, d = i % 84;
        float s = 0.f;
        for (int j = 0; j < 84; ++j)
            s = fmaf(shw[o * 84 + j], ew[((size_t)e * 84 + j) * 84 + d], s);
        C[e * 840 + i] = s;
    }
    if (tid < 10) {
        float s = 0.f;
        for (int j = 0; j < 84; ++j) s = fmaf(shw[tid * 84 + j], seb[e * 84 + j], s);
        hb2[e * 10 + tid] = s;
    }
}

// ---------------- tail: fc2+relu, gate, top2-softmax, MoE(composed)+head ----------------
__global__ __launch_bounds__(256) void k_tail(const float* __restrict__ h1,
                                              const float* __restrict__ f2w,
                                              const float* __restrict__ f2b,
                                              const float* __restrict__ gw,
                                              const float* __restrict__ Cw,
                                              const float* __restrict__ hb2,
                                              const float* __restrict__ headb,
                                              float* __restrict__ out) {
    __shared__ float sh1[64 * 120];
    __shared__ float sfw[84 * 121];
    __shared__ float sfb[84];
    __shared__ float sgw[672];
    __shared__ float sh[64 * 85];
    __shared__ float sC[6800];
    __shared__ float shb2[80];
    __shared__ float shb[10];
    __shared__ float slog[64 * 9];
    __shared__ float swt[128];
    __shared__ int   sei[128];
    const int tid = threadIdx.x;
    const int n0 = blockIdx.x * 64;

    {
        const float4* g = (const float4*)(h1 + (size_t)n0 * 120);
        float4* s = (float4*)sh1;
        for (int i = tid; i < 1920; i += 256) s[i] = g[i];
    }
    for (int i = tid; i < 2520; i += 256) {
        int o = i / 30, k4 = (i % 30) * 4;
        float4 v = *(const float4*)(f2w + (size_t)o * 120 + k4);
        float* d = sfw + o * 121 + k4;
        d[0] = v.x; d[1] = v.y; d[2] = v.z; d[3] = v.w;
    }
    for (int i = tid; i < 6720; i += 256) sC[(i / 84) * 85 + (i % 84)] = Cw[i];
    for (int i = tid; i < 672; i += 256) sgw[i] = gw[i];
    if (tid < 84) sfb[tid] = f2b[tid];
    if (tid < 80) shb2[tid] = hb2[tid];
    if (tid < 10) shb[tid] = headb[tid];
    __syncthreads();

    for (int i = tid; i < 5376; i += 256) {
        const int t = i / 84, o = i % 84;
        const float* a = sh1 + t * 120;
        const float* wr = sfw + o * 121;
        float s = 0.f;
        #pragma unroll 8
        for (int k = 0; k < 120; ++k) s = fmaf(a[k], wr[k], s);
        sh[t * 85 + o] = fmaxf(s + sfb[o], 0.f);
    }
    __syncthreads();

    for (int i = tid; i < 512; i += 256) {
        const int t = i / 8, e = i % 8;
        const float* a = sh + t * 85;
        float s = 0.f;
        #pragma unroll 4
        for (int d = 0; d < 84; ++d) s = fmaf(a[d], sgw[d * 8 + e], s);
        slog[t * 9 + e] = s;
    }
    __syncthreads();

    if (tid < 64) {
        const float* l = slog + tid * 9;
        float m1 = l[0]; int i1 = 0;
        #pragma unroll
        for (int e = 1; e < 8; ++e) if (l[e] > m1) { m1 = l[e]; i1 = e; }
        float m2 = -1e30f; int i2 = 0;
        #pragma unroll
        for (int e = 0; e < 8; ++e) if (e != i1 && l[e] > m2) { m2 = l[e]; i2 = e; }
        const float r = expf(m2 - m1);
        const float inv = 1.f / (1.f + r);
        swt[tid * 2] = inv; swt[tid * 2 + 1] = r * inv;
        sei[tid * 2] = i1; sei[tid * 2 + 1] = i2;
    }
    __syncthreads();

    for (int i = tid; i < 640; i += 256) {
        const int t = i / 10, o = i % 10;
        const float* a = sh + t * 85;
        const float w0 = swt[t * 2], w1 = swt[t * 2 + 1];
        const int e0 = sei[t * 2], e1 = sei[t * 2 + 1];
        const float* c0 = sC + (e0 * 10 + o) * 85;
        const float* c1 = sC + (e1 * 10 + o) * 85;
        float s0 = 0.f, s1 = 0.f;
        #pragma unroll 4
        for (int d = 0; d < 84; ++d) {
            s0 = fmaf(a[d], c0[d], s0);
            s1 = fmaf(a[d], c1[d], s1);
        }
        out[(size_t)(n0 + t) * 10 + o] =
            shb[o] + w0 * (s0 + shb2[e0 * 10 + o]) + w1 * (s1 + shb2[e1 * 10 + o]);
    }
}

extern "C" void kernel_launch(void* const* d_in, const int* in_sizes, int n_in,
                              void* d_out, int out_size, void* d_ws, size_t ws_size,
                              hipStream_t stream) {
    const float* x   = (const float*)d_in[0];
    const float* c1w = (const float*)d_in[1];
    const float* c1b = (const float*)d_in[2];
    const float* c2w = (const float*)d_in[3];
    const float* c2b = (const float*)d_in[4];
    const float* f1w = (const float*)d_in[5];
    const float* f1b = (const float*)d_in[6];
    const float* f2w = (const float*)d_in[7];
    const float* f2b = (const float*)d_in[8];
    const float* gw  = (const float*)d_in[9];
    const float* ew  = (const float*)d_in[10];
    const float* eb  = (const float*)d_in[11];
    const float* hw  = (const float*)d_in[12];
    const float* hb  = (const float*)d_in[13];
    float* out = (float*)d_out;

    const int N = in_sizes[0] / 3072;   // 16384

    float* ws = (float*)d_ws;
    uint*  p1  = (uint*)ws;                    // N*1176 uints (packed hi/lo)
    float* p2  = ws + (size_t)N * 1176;        // N*400
    float* h1  = p2 + (size_t)N * 400;         // N*120
    float* C   = h1 + (size_t)N * 120;         // 6720
    float* hb2 = C + 6720;                     // 80

    k_conv1<<<N / 2, 256, 0, stream>>>(x, c1w, c1b, p1);
    k_conv2<<<N / 4, 256, 0, stream>>>(p1, c2w, c2b, p2);
    k_fc1<<<N / 64, 256, 0, stream>>>(p2, f1w, f1b, h1);
    k_compose<<<8, 256, 0, stream>>>(ew, eb, hw, C, hb2);
    k_tail<<<N / 64, 256, 0, stream>>>(h1, f2w, f2b, gw, C, hb2, hb, out);
}

// Round 8
// 363.966 us; speedup vs baseline: 2.1292x; 1.0153x over previous
//
#include <hip/hip_runtime.h>
#include <math.h>

typedef _Float16 half8 __attribute__((ext_vector_type(8)));
typedef float f32x4 __attribute__((ext_vector_type(4)));

// split fp32 -> (hi,lo) fp16 pair packed in one uint (hi in low 16, lo in high 16)
__device__ inline uint splitpack(float v) {
    _Float16 h = (_Float16)v;
    float r = v - (float)h;
    _Float16 l = (_Float16)r;
    return (uint)__builtin_bit_cast(unsigned short, h) |
           ((uint)__builtin_bit_cast(unsigned short, l) << 16);
}
__device__ inline _Float16 lo16h(uint u) { return __builtin_bit_cast(_Float16, (unsigned short)(u & 0xffffu)); }
__device__ inline _Float16 hi16h(uint u) { return __builtin_bit_cast(_Float16, (unsigned short)(u >> 16)); }
__device__ inline uint packhh(_Float16 a, _Float16 b) {
    return (uint)__builtin_bit_cast(unsigned short, a) |
           ((uint)__builtin_bit_cast(unsigned short, b) << 16);
}
// pool-partner max via DPP row_ror:8 (lane^8 within 16-lane row) — no LDS traffic
__device__ inline float dpp_max8(float v) {
    int x = __builtin_amdgcn_mov_dpp(__builtin_bit_cast(int, v), 0x128, 0xf, 0xf, true);
    return fmaxf(v, __builtin_bit_cast(float, x));
}

// ---------------- conv1: split-fp16 MFMA, dx-in-N, SoA hi/lo LDS, perm-free fragments ----------------
// x:[N,3,32,32] -> p1:[N,6,14,14] packed uint.
// GEMM per image: M=392 (r=qx*28+y), N cols=(dx,c) 12/16, K=96 (90 real).
// K-slot (ks,g,jj): pi=jj>>1, e=jj&1; rho=g*4+pi (15=pad->clamp14,B=0); ci=rho/5, ky=rho%5; kxp=ks*2+e.
// LDS SoA per img: hi[3*32*34] halves then lo[...] (+6528B const offset).
// Fragment = 4x ds_read_b32 pairs per half -> half8 directly, zero v_perm.
__global__ __launch_bounds__(256) void k_conv1(const float* __restrict__ x,
                                               const float* __restrict__ w,
                                               const float* __restrict__ b,
                                               uint* __restrict__ p1) {
    __shared__ uint simg[6544];           // 2 imgs * (1632 hi + 1632 lo) dwords
    __shared__ uint sB[3 * 64 * 8];       // 6 KB
    __shared__ float sb[6];
    const int tid  = threadIdx.x;
    const int lane = tid & 63;
    const int wv   = tid >> 6;
    const int n0   = blockIdx.x * 2;

    // stage 2 images fp32 -> SoA split-fp16 (RTN hi, RTN lo)
    for (int i = tid; i < 1536; i += 256) {
        int im = i / 768;
        int rem = i - im * 768;
        int plane = rem >> 8, rr = (rem & 255) >> 3, c2 = (rem & 7) << 1;
        float4 v = *(const float4*)(x + ((size_t)(n0 + im) * 3 + plane) * 1024 + rr * 32 + (c2 << 1));
        _Float16 h0 = (_Float16)v.x, h1 = (_Float16)v.y, h2 = (_Float16)v.z, h3 = (_Float16)v.w;
        _Float16 l0 = (_Float16)(v.x - (float)h0), l1 = (_Float16)(v.y - (float)h1);
        _Float16 l2 = (_Float16)(v.z - (float)h2), l3 = (_Float16)(v.w - (float)h3);
        int base = im * 3264 + plane * 544 + rr * 17 + c2;
        simg[base]        = packhh(h0, h1);
        simg[base + 1]    = packhh(h2, h3);
        simg[base + 1632] = packhh(l0, l1);
        simg[base + 1633] = packhh(l2, l3);
    }
    // B fragments under the (pairi=ks, rb=g) permutation
    for (int p = tid; p < 192; p += 256) {
        int ks = p >> 6, l = p & 63;
        int colb = l & 15, g = l >> 4;
        int c = colb & 7, dx = colb >> 3;
        #pragma unroll
        for (int jj = 0; jj < 8; ++jj) {
            int pi = jj >> 1, e = jj & 1;
            int rho = g * 4 + pi;
            float val = 0.f;
            if (rho < 15 && c < 6) {
                int ci = rho / 5, ky = rho % 5;
                int kx = ks * 2 + e - dx;
                if (kx >= 0 && kx < 5) val = w[c * 75 + ci * 25 + ky * 5 + kx];
            }
            sB[p * 8 + jj] = splitpack(val);
        }
    }
    if (tid < 6) sb[tid] = b[tid];
    __syncthreads();

    const int g = lane >> 4;
    int poff[12];                          // dword offsets (pair base within hi-array)
    #pragma unroll
    for (int i = 0; i < 12; ++i) {
        int ks = i >> 2, pi = i & 3;
        int rho = g * 4 + pi;
        if (rho > 14) rho = 14;            // pad slot: safe in-bounds read, B=0
        poff[i] = (rho / 5) * 544 + (rho % 5) * 17 + ks;
    }
    half8 bh[3], bl[3];
    #pragma unroll
    for (int ks = 0; ks < 3; ++ks)
        #pragma unroll
        for (int jj = 0; jj < 8; ++jj) {
            uint u = sB[(ks * 64 + lane) * 8 + jj];
            bh[ks][jj] = lo16h(u); bl[ks][jj] = hi16h(u);
        }

    const int colb = lane & 15;
    const int c  = colb & 7, dx = colb >> 3;
    const int qr = lane >> 4;
    const float bias = (c < 6) ? sb[c] : 0.f;

    for (int t = wv; t < 50; t += 4) {
        int im = (t >= 25) ? 1 : 0;
        int tl = t - im * 25;
        const uint* img = simg + im * 3264;
        int r = tl * 16 + colb; if (r > 391) r = 391;
        int qx = (r * 586) >> 14;          // r/28 for r<392
        int y  = r - qx * 28;
        int base_dw = y * 17 + qx;
        f32x4 acc2[2] = {{0.f,0.f,0.f,0.f},{0.f,0.f,0.f,0.f}};
        int pp = 0;
        #pragma unroll
        for (int ks = 0; ks < 3; ++ks) {
            uint hu[4], lu[4];
            #pragma unroll
            for (int pi = 0; pi < 4; ++pi) {
                const uint* ap = img + base_dw + poff[ks * 4 + pi];
                hu[pi] = ap[0];
                lu[pi] = ap[1632];
            }
            uint4 hv; hv.x = hu[0]; hv.y = hu[1]; hv.z = hu[2]; hv.w = hu[3];
            uint4 lv; lv.x = lu[0]; lv.y = lu[1]; lv.z = lu[2]; lv.w = lu[3];
            half8 ah = __builtin_bit_cast(half8, hv);
            half8 al = __builtin_bit_cast(half8, lv);
            acc2[pp & 1] = __builtin_amdgcn_mfma_f32_16x16x32_f16(ah, bh[ks], acc2[pp & 1], 0, 0, 0); ++pp;
            acc2[pp & 1] = __builtin_amdgcn_mfma_f32_16x16x32_f16(ah, bl[ks], acc2[pp & 1], 0, 0, 0); ++pp;
            acc2[pp & 1] = __builtin_amdgcn_mfma_f32_16x16x32_f16(al, bh[ks], acc2[pp & 1], 0, 0, 0); ++pp;
        }
        f32x4 acc;
        #pragma unroll
        for (int i = 0; i < 4; ++i) acc[i] = acc2[0][i] + acc2[1][i];

        // pool: y-pairs in regs, dx-partner via DPP (lane^8)
        float p01 = dpp_max8(fmaxf(acc[0], acc[1]));
        float p23 = dpp_max8(fmaxf(acc[2], acc[3]));
        if (dx == 0 && c < 6) {
            uint* outb = p1 + ((size_t)(n0 + im) * 6 + c) * 196;
            int r0 = tl * 16 + qr * 4;
            if (r0 + 1 < 392) {
                int qx0 = (r0 * 586) >> 14, y0 = r0 - qx0 * 28;
                outb[(y0 >> 1) * 14 + qx0] = splitpack(fmaxf(p01 + bias, 0.f));
            }
            int r2 = r0 + 2;
            if (r2 + 1 < 392) {
                int qx2 = (r2 * 586) >> 14, y2 = r2 - qx2 * 28;
                outb[(y2 >> 1) * 14 + qx2] = splitpack(fmaxf(p23 + bias, 0.f));
            }
        }
    }
}

// ---------------- conv2 via split-fp16 MFMA: p1 packed -> p2:[N,400] fp32 ----------------
__global__ __launch_bounds__(256) void k_conv2(const uint* __restrict__ p1,
                                               const float* __restrict__ w,
                                               const float* __restrict__ b,
                                               float* __restrict__ p2) {
    __shared__ uint simg[4 * 1260];
    __shared__ uint sB[5 * 64 * 8];
    __shared__ float sb[16];
    const int tid  = threadIdx.x;
    const int lane = tid & 63;
    const int wv   = tid >> 6;
    const int n0   = blockIdx.x * 4;

    for (int i = tid; i < 4704; i += 256) {
        int img = i / 1176, rem = i % 1176;
        int c = rem / 196, rr = rem % 196;
        int y = rr / 14, xx = rr % 14;
        simg[img * 1260 + c * 210 + y * 15 + xx] = p1[(size_t)(n0 + img) * 1176 + rem];
    }
    for (int p = tid; p < 320; p += 256) {
        int ks = p >> 6, l = p & 63;
        int nn = l & 15, g = l >> 4;
        #pragma unroll
        for (int j = 0; j < 8; ++j) {
            int k = ks * 32 + g * 8 + j;
            float wv_ = (k < 150) ? w[nn * 150 + k] : 0.f;
            sB[p * 8 + j] = splitpack(wv_);
        }
    }
    if (tid < 16) sb[tid] = b[tid];
    __syncthreads();

    const int qw = (lane & 15) >> 2;
    const int dy = (lane >> 1) & 1, dx = lane & 1;
    const int g  = lane >> 4;
    int offs[40];
    #pragma unroll
    for (int ks = 0; ks < 5; ++ks)
        #pragma unroll
        for (int j = 0; j < 8; ++j) {
            int k = ks * 32 + g * 8 + j;
            int o = 0;
            if (k < 150) { int ci = k / 25, r = k % 25; o = ci * 210 + (r / 5) * 15 + (r % 5); }
            offs[ks * 8 + j] = o;
        }
    half8 bh[5], bl[5];
    #pragma unroll
    for (int ks = 0; ks < 5; ++ks)
        #pragma unroll
        for (int j = 0; j < 8; ++j) {
            uint u = sB[(ks * 64 + lane) * 8 + j];
            bh[ks][j] = lo16h(u); bl[ks][j] = hi16h(u);
        }

    const uint* img = simg + wv * 1260;
    const int n  = n0 + wv;
    const int cc = lane & 15;
    const int qr = lane >> 4;
    const float bias = sb[cc];
    float* outb = p2 + (size_t)n * 400 + cc * 25;

    for (int t = 0; t < 7; ++t) {
        int qa = t * 4 + qw; if (qa > 24) qa = 24;
        int qy = qa / 5, qx = qa % 5;
        int base = (2 * qy + dy) * 15 + (2 * qx + dx);
        f32x4 acc = {0.f, 0.f, 0.f, 0.f};
        #pragma unroll
        for (int ks = 0; ks < 5; ++ks) {
            uint up[8];
            #pragma unroll
            for (int j = 0; j < 8; ++j) up[j] = img[base + offs[ks * 8 + j]];
            half8 ah, al;
            #pragma unroll
            for (int j = 0; j < 8; ++j) { ah[j] = lo16h(up[j]); al[j] = hi16h(up[j]); }
            acc = __builtin_amdgcn_mfma_f32_16x16x32_f16(ah, bh[ks], acc, 0, 0, 0);
            acc = __builtin_amdgcn_mfma_f32_16x16x32_f16(ah, bl[ks], acc, 0, 0, 0);
            acc = __builtin_amdgcn_mfma_f32_16x16x32_f16(al, bh[ks], acc, 0, 0, 0);
        }
        int qc = t * 4 + qr;
        if (qc < 25) {
            float m = fmaxf(fmaxf(acc[0], acc[1]), fmaxf(acc[2], acc[3]));
            outb[qc] = fmaxf(m + bias, 0.f);
        }
    }
}

// ---------------- fc1: [N,400] @ [120,400]^T + relu -> h1:[N,120] ----------------
__global__ __launch_bounds__(256) void k_fc1(const float* __restrict__ p2,
                                             const float* __restrict__ w,
                                             const float* __restrict__ b,
                                             float* __restrict__ h1) {
    __shared__ float sa[64 * 100];
    __shared__ float swt[120 * 101];
    const int tid = threadIdx.x;
    const int n0 = blockIdx.x * 64;
    const int tc = tid % 30, tr = tid / 30;
    float acc[8][4];
    #pragma unroll
    for (int i = 0; i < 8; ++i)
        #pragma unroll
        for (int j = 0; j < 4; ++j) acc[i][j] = 0.f;

    for (int kt = 0; kt < 4; ++kt) {
        __syncthreads();
        for (int i = tid; i < 1600; i += 256) {
            int r = i / 25, k4 = (i % 25) * 4;
            float4 v = *(const float4*)(p2 + (size_t)(n0 + r) * 400 + kt * 100 + k4);
            *(float4*)(sa + r * 100 + k4) = v;
        }
        for (int i = tid; i < 3000; i += 256) {
            int c = i / 25, k4 = (i % 25) * 4;
            float4 v = *(const float4*)(w + (size_t)c * 400 + kt * 100 + k4);
            float* d = swt + c * 101 + k4;
            d[0] = v.x; d[1] = v.y; d[2] = v.z; d[3] = v.w;
        }
        __syncthreads();
        if (tr < 8) {
            #pragma unroll 4
            for (int k = 0; k < 100; ++k) {
                float av[8], wv[4];
                #pragma unroll
                for (int i = 0; i < 8; ++i) av[i] = sa[(tr * 8 + i) * 100 + k];
                #pragma unroll
                for (int j = 0; j < 4; ++j) wv[j] = swt[(tc * 4 + j) * 101 + k];
                #pragma unroll
                for (int i = 0; i < 8; ++i)
                    #pragma unroll
                    for (int j = 0; j < 4; ++j) acc[i][j] = fmaf(av[i], wv[j], acc[i][j]);
            }
        }
    }
    if (tr < 8) {
        #pragma unroll
        for (int j = 0; j < 4; ++j) {
            const int o = tc * 4 + j;
            const float bo = b[o];
            #pragma unroll
            for (int i = 0; i < 8; ++i) {
                const int rr = n0 + tr * 8 + i;
                h1[(size_t)rr * 120 + o] = fmaxf(acc[i][j] + bo, 0.f);
            }
        }
    }
}

// ---------------- compose: C[e][o][d] = sum_j head_w[o][j]*expert_w[e][j][d] ----------------
__global__ __launch_bounds__(256) void k_compose(const float* __restrict__ ew,
                                                 const float* __restrict__ eb,
                                                 const float* __restrict__ hw,
                                                 float* __restrict__ C,
                                                 float* __restrict__ hb2) {
    __shared__ float shw[840];
    __shared__ float seb[672];
    const int e = blockIdx.x, tid = threadIdx.x;
    for (int i = tid; i < 840; i += 256) shw[i] = hw[i];
    for (int i = tid; i < 672; i += 256) seb[i] = eb[i];
    __syncthreads();
    for (int i = tid; i < 840; i += 256) {
        int o = i / 84, d = i % 84;
        float s = 0.f;
        for (int j = 0; j < 84; ++j)
            s = fmaf(shw[o * 84 + j], ew[((size_t)e * 84 + j) * 84 + d], s);
        C[e * 840 + i] = s;
    }
    if (tid < 10) {
        float s = 0.f;
        for (int j = 0; j < 84; ++j) s = fmaf(shw[tid * 84 + j], seb[e * 84 + j], s);
        hb2[e * 10 + tid] = s;
    }
}

// ---------------- tail: fc2+relu, gate, top2-softmax, MoE(composed)+head ----------------
__global__ __launch_bounds__(256) void k_tail(const float* __restrict__ h1,
                                              const float* __restrict__ f2w,
                                              const float* __restrict__ f2b,
                                              const float* __restrict__ gw,
                                              const float* __restrict__ Cw,
                                              const float* __restrict__ hb2,
                                              const float* __restrict__ headb,
                                              float* __restrict__ out) {
    __shared__ float sh1[64 * 120];
    __shared__ float sfw[84 * 121];
    __shared__ float sfb[84];
    __shared__ float sgw[672];
    __shared__ float sh[64 * 85];
    __shared__ float sC[6800];
    __shared__ float shb2[80];
    __shared__ float shb[10];
    __shared__ float slog[64 * 9];
    __shared__ float swt[128];
    __shared__ int   sei[128];
    const int tid = threadIdx.x;
    const int n0 = blockIdx.x * 64;

    {
        const float4* g = (const float4*)(h1 + (size_t)n0 * 120);
        float4* s = (float4*)sh1;
        for (int i = tid; i < 1920; i += 256) s[i] = g[i];
    }
    for (int i = tid; i < 2520; i += 256) {
        int o = i / 30, k4 = (i % 30) * 4;
        float4 v = *(const float4*)(f2w + (size_t)o * 120 + k4);
        float* d = sfw + o * 121 + k4;
        d[0] = v.x; d[1] = v.y; d[2] = v.z; d[3] = v.w;
    }
    for (int i = tid; i < 6720; i += 256) sC[(i / 84) * 85 + (i % 84)] = Cw[i];
    for (int i = tid; i < 672; i += 256) sgw[i] = gw[i];
    if (tid < 84) sfb[tid] = f2b[tid];
    if (tid < 80) shb2[tid] = hb2[tid];
    if (tid < 10) shb[tid] = headb[tid];
    __syncthreads();

    for (int i = tid; i < 5376; i += 256) {
        const int t = i / 84, o = i % 84;
        const float* a = sh1 + t * 120;
        const float* wr = sfw + o * 121;
        float s = 0.f;
        #pragma unroll 8
        for (int k = 0; k < 120; ++k) s = fmaf(a[k], wr[k], s);
        sh[t * 85 + o] = fmaxf(s + sfb[o], 0.f);
    }
    __syncthreads();

    for (int i = tid; i < 512; i += 256) {
        const int t = i / 8, e = i % 8;
        const float* a = sh + t * 85;
        float s = 0.f;
        #pragma unroll 4
        for (int d = 0; d < 84; ++d) s = fmaf(a[d], sgw[d * 8 + e], s);
        slog[t * 9 + e] = s;
    }
    __syncthreads();

    if (tid < 64) {
        const float* l = slog + tid * 9;
        float m1 = l[0]; int i1 = 0;
        #pragma unroll
        for (int e = 1; e < 8; ++e) if (l[e] > m1) { m1 = l[e]; i1 = e; }
        float m2 = -1e30f; int i2 = 0;
        #pragma unroll
        for (int e = 0; e < 8; ++e) if (e != i1 && l[e] > m2) { m2 = l[e]; i2 = e; }
        const float r = expf(m2 - m1);
        const float inv = 1.f / (1.f + r);
        swt[tid * 2] = inv; swt[tid * 2 + 1] = r * inv;
        sei[tid * 2] = i1; sei[tid * 2 + 1] = i2;
    }
    __syncthreads();

    for (int i = tid; i < 640; i += 256) {
        const int t = i / 10, o = i % 10;
        const float* a = sh + t * 85;
        const float w0 = swt[t * 2], w1 = swt[t * 2 + 1];
        const int e0 = sei[t * 2], e1 = sei[t * 2 + 1];
        const float* c0 = sC + (e0 * 10 + o) * 85;
        const float* c1 = sC + (e1 * 10 + o) * 85;
        float s0 = 0.f, s1 = 0.f;
        #pragma unroll 4
        for (int d = 0; d < 84; ++d) {
            s0 = fmaf(a[d], c0[d], s0);
            s1 = fmaf(a[d], c1[d], s1);
        }
        out[(size_t)(n0 + t) * 10 + o] =
            shb[o] + w0 * (s0 + shb2[e0 * 10 + o]) + w1 * (s1 + shb2[e1 * 10 + o]);
    }
}

extern "C" void kernel_launch(void* const* d_in, const int* in_sizes, int n_in,
                              void* d_out, int out_size, void* d_ws, size_t ws_size,
                              hipStream_t stream) {
    const float* x   = (const float*)d_in[0];
    const float* c1w = (const float*)d_in[1];
    const float* c1b = (const float*)d_in[2];
    const float* c2w = (const float*)d_in[3];
    const float* c2b = (const float*)d_in[4];
    const float* f1w = (const float*)d_in[5];
    const float* f1b = (const float*)d_in[6];
    const float* f2w = (const float*)d_in[7];
    const float* f2b = (const float*)d_in[8];
    const float* gw  = (const float*)d_in[9];
    const float* ew  = (const float*)d_in[10];
    const float* eb  = (const float*)d_in[11];
    const float* hw  = (const float*)d_in[12];
    const float* hb  = (const float*)d_in[13];
    float* out = (float*)d_out;

    const int N = in_sizes[0] / 3072;   // 16384

    float* ws = (float*)d_ws;
    uint*  p1  = (uint*)ws;                    // N*1176 uints (packed hi/lo)
    float* p2  = ws + (size_t)N * 1176;        // N*400
    float* h1  = p2 + (size_t)N * 400;         // N*120
    float* C   = h1 + (size_t)N * 120;         // 6720
    float* hb2 = C + 6720;                     // 80

    k_conv1<<<N / 2, 256, 0, stream>>>(x, c1w, c1b, p1);
    k_conv2<<<N / 4, 256, 0, stream>>>(p1, c2w, c2b, p2);
    k_fc1<<<N / 64, 256, 0, stream>>>(p2, f1w, f1b, h1);
    k_compose<<<8, 256, 0, stream>>>(ew, eb, hw, C, hb2);
    k_tail<<<N / 64, 256, 0, stream>>>(h1, f2w, f2b, gw, C, hb2, hb, out);
}

// Round 9
// 359.050 us; speedup vs baseline: 2.1584x; 1.0137x over previous
//
#include <hip/hip_runtime.h>
#include <math.h>

typedef _Float16 half8 __attribute__((ext_vector_type(8)));
typedef float f32x4 __attribute__((ext_vector_type(4)));

// split fp32 -> (hi,lo) fp16 pair packed in one uint (hi in low 16, lo in high 16)
__device__ inline uint splitpack(float v) {
    _Float16 h = (_Float16)v;
    float r = v - (float)h;
    _Float16 l = (_Float16)r;
    return (uint)__builtin_bit_cast(unsigned short, h) |
           ((uint)__builtin_bit_cast(unsigned short, l) << 16);
}
__device__ inline _Float16 lo16h(uint u) { return __builtin_bit_cast(_Float16, (unsigned short)(u & 0xffffu)); }
__device__ inline _Float16 hi16h(uint u) { return __builtin_bit_cast(_Float16, (unsigned short)(u >> 16)); }
__device__ inline uint packhh(_Float16 a, _Float16 b) {
    return (uint)__builtin_bit_cast(unsigned short, a) |
           ((uint)__builtin_bit_cast(unsigned short, b) << 16);
}
// pool-partner max via DPP row_ror:8 (lane^8 within 16-lane row) — no LDS traffic
__device__ inline float dpp_max8(float v) {
    int x = __builtin_amdgcn_mov_dpp(__builtin_bit_cast(int, v), 0x128, 0xf, 0xf, true);
    return fmaxf(v, __builtin_bit_cast(float, x));
}

// ---------------- conv1: split-fp16 MFMA, dx-in-N, row-interleaved hi/lo, ds_read2 pairs ----------------
// x:[N,3,32,32] -> p1:[N,6,14,14] packed uint.
// GEMM per image: M=392 (r=qx*28+y), N cols=(dx,c) 12/16, K=96 (90 real).
// K-slot (ks,g,jj): pi=jj>>1, e=jj&1; rho=g*4+pi (15=pad->clamp14,B=0); ci=rho/5, ky=rho%5; kxp=ks*2+e.
// LDS row (35 dwords, odd stride => conflict-free): [hi x-pairs 16][lo x-pairs 16][pad 3].
// Per (rho): 6 dwords at imm offsets {0,1,2,16,17,18} off one base -> 3x ds_read2_b32.
__global__ __launch_bounds__(256) void k_conv1(const float* __restrict__ x,
                                               const float* __restrict__ w,
                                               const float* __restrict__ b,
                                               uint* __restrict__ p1) {
    __shared__ uint simg[6720];           // 2 imgs * 3 planes * 32 rows * 35 dwords (26.9 KB)
    __shared__ uint sB[3 * 64 * 8];       // 6 KB
    __shared__ float sb[6];
    const int tid  = threadIdx.x;
    const int lane = tid & 63;
    const int wv   = tid >> 6;
    const int n0   = blockIdx.x * 2;

    // stage 2 images fp32 -> row-interleaved split-fp16
    for (int i = tid; i < 1536; i += 256) {
        int im = i / 768;
        int rem = i - im * 768;
        int plane = rem >> 8, rr = (rem & 255) >> 3, f = rem & 7;
        float4 v = *(const float4*)(x + ((size_t)(n0 + im) * 3 + plane) * 1024 + rr * 32 + f * 4);
        _Float16 h0 = (_Float16)v.x, h1 = (_Float16)v.y, h2 = (_Float16)v.z, h3 = (_Float16)v.w;
        _Float16 l0 = (_Float16)(v.x - (float)h0), l1 = (_Float16)(v.y - (float)h1);
        _Float16 l2 = (_Float16)(v.z - (float)h2), l3 = (_Float16)(v.w - (float)h3);
        int base = im * 3360 + plane * 1120 + rr * 35 + f * 2;
        simg[base]      = packhh(h0, h1);
        simg[base + 1]  = packhh(h2, h3);
        simg[base + 16] = packhh(l0, l1);
        simg[base + 17] = packhh(l2, l3);
    }
    // B fragments under the (rho=g*4+pi, kxp=ks*2+e) permutation
    for (int p = tid; p < 192; p += 256) {
        int ks = p >> 6, l = p & 63;
        int colb = l & 15, g = l >> 4;
        int c = colb & 7, dx = colb >> 3;
        #pragma unroll
        for (int jj = 0; jj < 8; ++jj) {
            int pi = jj >> 1, e = jj & 1;
            int rho = g * 4 + pi;
            float val = 0.f;
            if (rho < 15 && c < 6) {
                int ci = rho / 5, ky = rho % 5;
                int kx = ks * 2 + e - dx;
                if (kx >= 0 && kx < 5) val = w[c * 75 + ci * 25 + ky * 5 + kx];
            }
            sB[p * 8 + jj] = splitpack(val);
        }
    }
    if (tid < 6) sb[tid] = b[tid];
    __syncthreads();

    const int g = lane >> 4;
    int poff[4];                           // per-rho row base offset (dwords)
    #pragma unroll
    for (int pi = 0; pi < 4; ++pi) {
        int rho = g * 4 + pi;
        if (rho > 14) rho = 14;            // pad slot: safe in-bounds read, B=0
        poff[pi] = (rho / 5) * 1120 + (rho % 5) * 35;
    }
    half8 bh[3], bl[3];
    #pragma unroll
    for (int ks = 0; ks < 3; ++ks)
        #pragma unroll
        for (int jj = 0; jj < 8; ++jj) {
            uint u = sB[(ks * 64 + lane) * 8 + jj];
            bh[ks][jj] = lo16h(u); bl[ks][jj] = hi16h(u);
        }

    const int colb = lane & 15;
    const int c  = colb & 7, dx = colb >> 3;
    const int qr = lane >> 4;
    const float bias = (c < 6) ? sb[c] : 0.f;

    for (int t = wv; t < 50; t += 4) {
        int im = (t >= 25) ? 1 : 0;
        int tl = t - im * 25;
        const uint* img = simg + im * 3360;
        int r = tl * 16 + colb; if (r > 391) r = 391;
        int qx = (r * 586) >> 14;          // r/28 for r<392
        int y  = r - qx * 28;
        int base_dw = y * 35 + qx;

        uint hu[3][4], lu[3][4];
        #pragma unroll
        for (int pi = 0; pi < 4; ++pi) {
            const uint* ap = img + base_dw + poff[pi];
            #pragma unroll
            for (int ks = 0; ks < 3; ++ks) {
                hu[ks][pi] = ap[ks];       // {0,1,2} + {16,17,18}: merges to 3x ds_read2_b32
                lu[ks][pi] = ap[16 + ks];
            }
        }
        f32x4 acc2[2] = {{0.f,0.f,0.f,0.f},{0.f,0.f,0.f,0.f}};
        int pp = 0;
        #pragma unroll
        for (int ks = 0; ks < 3; ++ks) {
            uint4 hv; hv.x = hu[ks][0]; hv.y = hu[ks][1]; hv.z = hu[ks][2]; hv.w = hu[ks][3];
            uint4 lv; lv.x = lu[ks][0]; lv.y = lu[ks][1]; lv.z = lu[ks][2]; lv.w = lu[ks][3];
            half8 ah = __builtin_bit_cast(half8, hv);
            half8 al = __builtin_bit_cast(half8, lv);
            acc2[pp & 1] = __builtin_amdgcn_mfma_f32_16x16x32_f16(ah, bh[ks], acc2[pp & 1], 0, 0, 0); ++pp;
            acc2[pp & 1] = __builtin_amdgcn_mfma_f32_16x16x32_f16(ah, bl[ks], acc2[pp & 1], 0, 0, 0); ++pp;
            acc2[pp & 1] = __builtin_amdgcn_mfma_f32_16x16x32_f16(al, bh[ks], acc2[pp & 1], 0, 0, 0); ++pp;
        }
        f32x4 acc;
        #pragma unroll
        for (int i = 0; i < 4; ++i) acc[i] = acc2[0][i] + acc2[1][i];

        // pool: y-pairs in regs, dx-partner via DPP (lane^8)
        float p01 = dpp_max8(fmaxf(acc[0], acc[1]));
        float p23 = dpp_max8(fmaxf(acc[2], acc[3]));
        if (dx == 0 && c < 6) {
            uint* outb = p1 + ((size_t)(n0 + im) * 6 + c) * 196;
            int r0 = tl * 16 + qr * 4;
            if (r0 + 1 < 392) {
                int qx0 = (r0 * 586) >> 14, y0 = r0 - qx0 * 28;
                outb[(y0 >> 1) * 14 + qx0] = splitpack(fmaxf(p01 + bias, 0.f));
            }
            int r2 = r0 + 2;
            if (r2 + 1 < 392) {
                int qx2 = (r2 * 586) >> 14, y2 = r2 - qx2 * 28;
                outb[(y2 >> 1) * 14 + qx2] = splitpack(fmaxf(p23 + bias, 0.f));
            }
        }
    }
}

// ---------------- conv2 via split-fp16 MFMA: p1 packed -> p2:[N,400] fp32 ----------------
__global__ __launch_bounds__(256) void k_conv2(const uint* __restrict__ p1,
                                               const float* __restrict__ w,
                                               const float* __restrict__ b,
                                               float* __restrict__ p2) {
    __shared__ uint simg[4 * 1260];
    __shared__ uint sB[5 * 64 * 8];
    __shared__ float sb[16];
    const int tid  = threadIdx.x;
    const int lane = tid & 63;
    const int wv   = tid >> 6;
    const int n0   = blockIdx.x * 4;

    for (int i = tid; i < 4704; i += 256) {
        int img = i / 1176, rem = i % 1176;
        int c = rem / 196, rr = rem % 196;
        int y = rr / 14, xx = rr % 14;
        simg[img * 1260 + c * 210 + y * 15 + xx] = p1[(size_t)(n0 + img) * 1176 + rem];
    }
    for (int p = tid; p < 320; p += 256) {
        int ks = p >> 6, l = p & 63;
        int nn = l & 15, g = l >> 4;
        #pragma unroll
        for (int j = 0; j < 8; ++j) {
            int k = ks * 32 + g * 8 + j;
            float wv_ = (k < 150) ? w[nn * 150 + k] : 0.f;
            sB[p * 8 + j] = splitpack(wv_);
        }
    }
    if (tid < 16) sb[tid] = b[tid];
    __syncthreads();

    const int qw = (lane & 15) >> 2;
    const int dy = (lane >> 1) & 1, dx = lane & 1;
    const int g  = lane >> 4;
    int offs[40];
    #pragma unroll
    for (int ks = 0; ks < 5; ++ks)
        #pragma unroll
        for (int j = 0; j < 8; ++j) {
            int k = ks * 32 + g * 8 + j;
            int o = 0;
            if (k < 150) { int ci = k / 25, r = k % 25; o = ci * 210 + (r / 5) * 15 + (r % 5); }
            offs[ks * 8 + j] = o;
        }
    half8 bh[5], bl[5];
    #pragma unroll
    for (int ks = 0; ks < 5; ++ks)
        #pragma unroll
        for (int j = 0; j < 8; ++j) {
            uint u = sB[(ks * 64 + lane) * 8 + j];
            bh[ks][j] = lo16h(u); bl[ks][j] = hi16h(u);
        }

    const uint* img = simg + wv * 1260;
    const int n  = n0 + wv;
    const int cc = lane & 15;
    const int qr = lane >> 4;
    const float bias = sb[cc];
    float* outb = p2 + (size_t)n * 400 + cc * 25;

    for (int t = 0; t < 7; ++t) {
        int qa = t * 4 + qw; if (qa > 24) qa = 24;
        int qy = qa / 5, qx = qa % 5;
        int base = (2 * qy + dy) * 15 + (2 * qx + dx);
        f32x4 acc = {0.f, 0.f, 0.f, 0.f};
        #pragma unroll
        for (int ks = 0; ks < 5; ++ks) {
            uint up[8];
            #pragma unroll
            for (int j = 0; j < 8; ++j) up[j] = img[base + offs[ks * 8 + j]];
            half8 ah, al;
            #pragma unroll
            for (int j = 0; j < 8; ++j) { ah[j] = lo16h(up[j]); al[j] = hi16h(up[j]); }
            acc = __builtin_amdgcn_mfma_f32_16x16x32_f16(ah, bh[ks], acc, 0, 0, 0);
            acc = __builtin_amdgcn_mfma_f32_16x16x32_f16(ah, bl[ks], acc, 0, 0, 0);
            acc = __builtin_amdgcn_mfma_f32_16x16x32_f16(al, bh[ks], acc, 0, 0, 0);
        }
        int qc = t * 4 + qr;
        if (qc < 25) {
            float m = fmaxf(fmaxf(acc[0], acc[1]), fmaxf(acc[2], acc[3]));
            outb[qc] = fmaxf(m + bias, 0.f);
        }
    }
}

// ---------------- fc1: [N,400] @ [120,400]^T + relu -> h1:[N,120] ----------------
__global__ __launch_bounds__(256) void k_fc1(const float* __restrict__ p2,
                                             const float* __restrict__ w,
                                             const float* __restrict__ b,
                                             float* __restrict__ h1) {
    __shared__ float sa[64 * 100];
    __shared__ float swt[120 * 101];
    const int tid = threadIdx.x;
    const int n0 = blockIdx.x * 64;
    const int tc = tid % 30, tr = tid / 30;
    float acc[8][4];
    #pragma unroll
    for (int i = 0; i < 8; ++i)
        #pragma unroll
        for (int j = 0; j < 4; ++j) acc[i][j] = 0.f;

    for (int kt = 0; kt < 4; ++kt) {
        __syncthreads();
        for (int i = tid; i < 1600; i += 256) {
            int r = i / 25, k4 = (i % 25) * 4;
            float4 v = *(const float4*)(p2 + (size_t)(n0 + r) * 400 + kt * 100 + k4);
            *(float4*)(sa + r * 100 + k4) = v;
        }
        for (int i = tid; i < 3000; i += 256) {
            int c = i / 25, k4 = (i % 25) * 4;
            float4 v = *(const float4*)(w + (size_t)c * 400 + kt * 100 + k4);
            float* d = swt + c * 101 + k4;
            d[0] = v.x; d[1] = v.y; d[2] = v.z; d[3] = v.w;
        }
        __syncthreads();
        if (tr < 8) {
            #pragma unroll 4
            for (int k = 0; k < 100; ++k) {
                float av[8], wv[4];
                #pragma unroll
                for (int i = 0; i < 8; ++i) av[i] = sa[(tr * 8 + i) * 100 + k];
                #pragma unroll
                for (int j = 0; j < 4; ++j) wv[j] = swt[(tc * 4 + j) * 101 + k];
                #pragma unroll
                for (int i = 0; i < 8; ++i)
                    #pragma unroll
                    for (int j = 0; j < 4; ++j) acc[i][j] = fmaf(av[i], wv[j], acc[i][j]);
            }
        }
    }
    if (tr < 8) {
        #pragma unroll
        for (int j = 0; j < 4; ++j) {
            const int o = tc * 4 + j;
            const float bo = b[o];
            #pragma unroll
            for (int i = 0; i < 8; ++i) {
                const int rr = n0 + tr * 8 + i;
                h1[(size_t)rr * 120 + o] = fmaxf(acc[i][j] + bo, 0.f);
            }
        }
    }
}

// ---------------- compose: C[e][o][d] = sum_j head_w[o][j]*expert_w[e][j][d] ----------------
__global__ __launch_bounds__(256) void k_compose(const float* __restrict__ ew,
                                                 const float* __restrict__ eb,
                                                 const float* __restrict__ hw,
                                                 float* __restrict__ C,
                                                 float* __restrict__ hb2) {
    __shared__ float shw[840];
    __shared__ float seb[672];
    const int e = blockIdx.x, tid = threadIdx.x;
    for (int i = tid; i < 840; i += 256) shw[i] = hw[i];
    for (int i = tid; i < 672; i += 256) seb[i] = eb[i];
    __syncthreads();
    for (int i = tid; i < 840; i += 256) {
        int o = i / 84, d = i % 84;
        float s = 0.f;
        for (int j = 0; j < 84; ++j)
            s = fmaf(shw[o * 84 + j], ew[((size_t)e * 84 + j) * 84 + d], s);
        C[e * 840 + i] = s;
    }
    if (tid < 10) {
        float s = 0.f;
        for (int j = 0; j < 84; ++j) s = fmaf(shw[tid * 84 + j], seb[e * 84 + j], s);
        hb2[e * 10 + tid] = s;
    }
}

// ---------------- tail: fc2+relu, gate, top2-softmax, MoE(composed)+head ----------------
__global__ __launch_bounds__(256) void k_tail(const float* __restrict__ h1,
                                              const float* __restrict__ f2w,
                                              const float* __restrict__ f2b,
                                              const float* __restrict__ gw,
                                              const float* __restrict__ Cw,
                                              const float* __restrict__ hb2,
                                              const float* __restrict__ headb,
                                              float* __restrict__ out) {
    __shared__ float sh1[64 * 120];
    __shared__ float sfw[84 * 121];
    __shared__ float sfb[84];
    __shared__ float sgw[672];
    __shared__ float sh[64 * 85];
    __shared__ float sC[6800];
    __shared__ float shb2[80];
    __shared__ float shb[10];
    __shared__ float slog[64 * 9];
    __shared__ float swt[128];
    __shared__ int   sei[128];
    const int tid = threadIdx.x;
    const int n0 = blockIdx.x * 64;

    {
        const float4* g = (const float4*)(h1 + (size_t)n0 * 120);
        float4* s = (float4*)sh1;
        for (int i = tid; i < 1920; i += 256) s[i] = g[i];
    }
    for (int i = tid; i < 2520; i += 256) {
        int o = i / 30, k4 = (i % 30) * 4;
        float4 v = *(const float4*)(f2w + (size_t)o * 120 + k4);
        float* d = sfw + o * 121 + k4;
        d[0] = v.x; d[1] = v.y; d[2] = v.z; d[3] = v.w;
    }
    for (int i = tid; i < 6720; i += 256) sC[(i / 84) * 85 + (i % 84)] = Cw[i];
    for (int i = tid; i < 672; i += 256) sgw[i] = gw[i];
    if (tid < 84) sfb[tid] = f2b[tid];
    if (tid < 80) shb2[tid] = hb2[tid];
    if (tid < 10) shb[tid] = headb[tid];
    __syncthreads();

    for (int i = tid; i < 5376; i += 256) {
        const int t = i / 84, o = i % 84;
        const float* a = sh1 + t * 120;
        const float* wr = sfw + o * 121;
        float s = 0.f;
        #pragma unroll 8
        for (int k = 0; k < 120; ++k) s = fmaf(a[k], wr[k], s);
        sh[t * 85 + o] = fmaxf(s + sfb[o], 0.f);
    }
    __syncthreads();

    for (int i = tid; i < 512; i += 256) {
        const int t = i / 8, e = i % 8;
        const float* a = sh + t * 85;
        float s = 0.f;
        #pragma unroll 4
        for (int d = 0; d < 84; ++d) s = fmaf(a[d], sgw[d * 8 + e], s);
        slog[t * 9 + e] = s;
    }
    __syncthreads();

    if (tid < 64) {
        const float* l = slog + tid * 9;
        float m1 = l[0]; int i1 = 0;
        #pragma unroll
        for (int e = 1; e < 8; ++e) if (l[e] > m1) { m1 = l[e]; i1 = e; }
        float m2 = -1e30f; int i2 = 0;
        #pragma unroll
        for (int e = 0; e < 8; ++e) if (e != i1 && l[e] > m2) { m2 = l[e]; i2 = e; }
        const float r = expf(m2 - m1);
        const float inv = 1.f / (1.f + r);
        swt[tid * 2] = inv; swt[tid * 2 + 1] = r * inv;
        sei[tid * 2] = i1; sei[tid * 2 + 1] = i2;
    }
    __syncthreads();

    for (int i = tid; i < 640; i += 256) {
        const int t = i / 10, o = i % 10;
        const float* a = sh + t * 85;
        const float w0 = swt[t * 2], w1 = swt[t * 2 + 1];
        const int e0 = sei[t * 2], e1 = sei[t * 2 + 1];
        const float* c0 = sC + (e0 * 10 + o) * 85;
        const float* c1 = sC + (e1 * 10 + o) * 85;
        float s0 = 0.f, s1 = 0.f;
        #pragma unroll 4
        for (int d = 0; d < 84; ++d) {
            s0 = fmaf(a[d], c0[d], s0);
            s1 = fmaf(a[d], c1[d], s1);
        }
        out[(size_t)(n0 + t) * 10 + o] =
            shb[o] + w0 * (s0 + shb2[e0 * 10 + o]) + w1 * (s1 + shb2[e1 * 10 + o]);
    }
}

extern "C" void kernel_launch(void* const* d_in, const int* in_sizes, int n_in,
                              void* d_out, int out_size, void* d_ws, size_t ws_size,
                              hipStream_t stream) {
    const float* x   = (const float*)d_in[0];
    const float* c1w = (const float*)d_in[1];
    const float* c1b = (const float*)d_in[2];
    const float* c2w = (const float*)d_in[3];
    const float* c2b = (const float*)d_in[4];
    const float* f1w = (const float*)d_in[5];
    const float* f1b = (const float*)d_in[6];
    const float* f2w = (const float*)d_in[7];
    const float* f2b = (const float*)d_in[8];
    const float* gw  = (const float*)d_in[9];
    const float* ew  = (const float*)d_in[10];
    const float* eb  = (const float*)d_in[11];
    const float* hw  = (const float*)d_in[12];
    const float* hb  = (const float*)d_in[13];
    float* out = (float*)d_out;

    const int N = in_sizes[0] / 3072;   // 16384

    float* ws = (float*)d_ws;
    uint*  p1  = (uint*)ws;                    // N*1176 uints (packed hi/lo)
    float* p2  = ws + (size_t)N * 1176;        // N*400
    float* h1  = p2 + (size_t)N * 400;         // N*120
    float* C   = h1 + (size_t)N * 120;         // 6720
    float* hb2 = C + 6720;                     // 80

    k_conv1<<<N / 2, 256, 0, stream>>>(x, c1w, c1b, p1);
    k_conv2<<<N / 4, 256, 0, stream>>>(p1, c2w, c2b, p2);
    k_fc1<<<N / 64, 256, 0, stream>>>(p2, f1w, f1b, h1);
    k_compose<<<8, 256, 0, stream>>>(ew, eb, hw, C, hb2);
    k_tail<<<N / 64, 256, 0, stream>>>(h1, f2w, f2b, gw, C, hb2, hb, out);
}

// Round 10
// 355.828 us; speedup vs baseline: 2.1779x; 1.0091x over previous
//
#include <hip/hip_runtime.h>
#include <math.h>

typedef _Float16 half8 __attribute__((ext_vector_type(8)));
typedef float f32x4 __attribute__((ext_vector_type(4)));

// split fp32 -> (hi,lo) fp16 pair packed in one uint (hi in low 16, lo in high 16)
__device__ inline uint splitpack(float v) {
    _Float16 h = (_Float16)v;
    float r = v - (float)h;
    _Float16 l = (_Float16)r;
    return (uint)__builtin_bit_cast(unsigned short, h) |
           ((uint)__builtin_bit_cast(unsigned short, l) << 16);
}
__device__ inline _Float16 lo16h(uint u) { return __builtin_bit_cast(_Float16, (unsigned short)(u & 0xffffu)); }
__device__ inline _Float16 hi16h(uint u) { return __builtin_bit_cast(_Float16, (unsigned short)(u >> 16)); }
__device__ inline uint packhh(_Float16 a, _Float16 b) {
    return (uint)__builtin_bit_cast(unsigned short, a) |
           ((uint)__builtin_bit_cast(unsigned short, b) << 16);
}
// pool-partner max via DPP row_ror:8 (lane^8 within 16-lane row) — no LDS traffic
__device__ inline float dpp_max8(float v) {
    int x = __builtin_amdgcn_mov_dpp(__builtin_bit_cast(int, v), 0x128, 0xf, 0xf, true);
    return fmaxf(v, __builtin_bit_cast(float, x));
}

// ---------------- conv1: split-fp16 MFMA, dx-in-N, row-interleaved hi/lo, 2-tile pipeline ----------------
// x:[N,3,32,32] -> p1:[N,6,14,14] packed uint.
// GEMM per image: M=392 (r=qx*28+y), N cols=(dx,c) 12/16, K=96 (90 real).
// K-slot (ks,g,jj): pi=jj>>1, e=jj&1; rho=g*4+pi (15=pad->clamp14,B=0); ci=rho/5, ky=rho%5; kxp=ks*2+e.
// LDS row (35 dwords): [hi x-pairs 16][lo x-pairs 16][pad 3]; per rho 3x ds_read2_b32.
// B-fragments computed per-lane into registers (no LDS) -> 26.9 KB LDS, 6 blocks/CU.
// Two tiles (t, t+4) pipelined per iteration for 2x independent chains.
__global__ __launch_bounds__(256) void k_conv1(const float* __restrict__ x,
                                               const float* __restrict__ w,
                                               const float* __restrict__ b,
                                               uint* __restrict__ p1) {
    __shared__ uint simg[6720];           // 2 imgs * 3 planes * 32 rows * 35 dwords (26.9 KB)
    const int tid  = threadIdx.x;
    const int lane = tid & 63;
    const int wv   = tid >> 6;
    const int n0   = blockIdx.x * 2;

    const int colb = lane & 15;
    const int c  = colb & 7, dx = colb >> 3;
    const int g  = lane >> 4;
    const int qr = g;

    // B fragments straight into registers (identical values the old sB held)
    half8 bh[3], bl[3];
    #pragma unroll
    for (int ks = 0; ks < 3; ++ks)
        #pragma unroll
        for (int jj = 0; jj < 8; ++jj) {
            int pi = jj >> 1, e = jj & 1;
            int rho = g * 4 + pi;
            float val = 0.f;
            if (rho < 15 && c < 6) {
                int ci = rho / 5, ky = rho % 5;
                int kx = ks * 2 + e - dx;
                if (kx >= 0 && kx < 5) val = w[c * 75 + ci * 25 + ky * 5 + kx];
            }
            _Float16 hh = (_Float16)val;
            bh[ks][jj] = hh;
            bl[ks][jj] = (_Float16)(val - (float)hh);
        }
    const float bias = (c < 6) ? b[c] : 0.f;

    // stage 2 images fp32 -> row-interleaved split-fp16
    for (int i = tid; i < 1536; i += 256) {
        int im = i / 768;
        int rem = i - im * 768;
        int plane = rem >> 8, rr = (rem & 255) >> 3, f = rem & 7;
        float4 v = *(const float4*)(x + ((size_t)(n0 + im) * 3 + plane) * 1024 + rr * 32 + f * 4);
        _Float16 h0 = (_Float16)v.x, h1 = (_Float16)v.y, h2 = (_Float16)v.z, h3 = (_Float16)v.w;
        _Float16 l0 = (_Float16)(v.x - (float)h0), l1 = (_Float16)(v.y - (float)h1);
        _Float16 l2 = (_Float16)(v.z - (float)h2), l3 = (_Float16)(v.w - (float)h3);
        int base = im * 3360 + plane * 1120 + rr * 35 + f * 2;
        simg[base]      = packhh(h0, h1);
        simg[base + 1]  = packhh(h2, h3);
        simg[base + 16] = packhh(l0, l1);
        simg[base + 17] = packhh(l2, l3);
    }
    __syncthreads();

    int poff[4];                           // per-rho row base offset (dwords)
    #pragma unroll
    for (int pi = 0; pi < 4; ++pi) {
        int rho = g * 4 + pi;
        if (rho > 14) rho = 14;            // pad slot: safe in-bounds read, B=0
        poff[pi] = (rho / 5) * 1120 + (rho % 5) * 35;
    }

    for (int t0 = wv; t0 < 50; t0 += 8) {
        const int t1 = (t0 + 4 < 50) ? (t0 + 4) : t0;   // second tile (or dup)
        const int im0 = (t0 >= 25) ? 1 : 0, tl0 = t0 - im0 * 25;
        const int im1 = (t1 >= 25) ? 1 : 0, tl1 = t1 - im1 * 25;
        int r0c = tl0 * 16 + colb; if (r0c > 391) r0c = 391;
        int r1c = tl1 * 16 + colb; if (r1c > 391) r1c = 391;
        int qx0 = (r0c * 586) >> 14, yy0 = r0c - qx0 * 28;
        int qx1 = (r1c * 586) >> 14, yy1 = r1c - qx1 * 28;
        const uint* base0 = simg + im0 * 3360 + yy0 * 35 + qx0;
        const uint* base1 = simg + im1 * 3360 + yy1 * 35 + qx1;

        f32x4 A0[2] = {{0.f,0.f,0.f,0.f},{0.f,0.f,0.f,0.f}};
        f32x4 A1[2] = {{0.f,0.f,0.f,0.f},{0.f,0.f,0.f,0.f}};
        int c0 = 0, c1 = 0;
        #pragma unroll
        for (int ks = 0; ks < 3; ++ks) {
            uint h0[4], l0[4], h1[4], l1[4];
            #pragma unroll
            for (int pi = 0; pi < 4; ++pi) {
                const uint* a0p = base0 + poff[pi];
                const uint* a1p = base1 + poff[pi];
                h0[pi] = a0p[ks];  l0[pi] = a0p[16 + ks];   // {ks, ks+16}: ds_read2_b32
                h1[pi] = a1p[ks];  l1[pi] = a1p[16 + ks];
            }
            uint4 hv0; hv0.x = h0[0]; hv0.y = h0[1]; hv0.z = h0[2]; hv0.w = h0[3];
            uint4 lv0; lv0.x = l0[0]; lv0.y = l0[1]; lv0.z = l0[2]; lv0.w = l0[3];
            uint4 hv1; hv1.x = h1[0]; hv1.y = h1[1]; hv1.z = h1[2]; hv1.w = h1[3];
            uint4 lv1; lv1.x = l1[0]; lv1.y = l1[1]; lv1.z = l1[2]; lv1.w = l1[3];
            half8 ah0 = __builtin_bit_cast(half8, hv0);
            half8 al0 = __builtin_bit_cast(half8, lv0);
            half8 ah1 = __builtin_bit_cast(half8, hv1);
            half8 al1 = __builtin_bit_cast(half8, lv1);
            A0[c0 & 1] = __builtin_amdgcn_mfma_f32_16x16x32_f16(ah0, bh[ks], A0[c0 & 1], 0, 0, 0); ++c0;
            A1[c1 & 1] = __builtin_amdgcn_mfma_f32_16x16x32_f16(ah1, bh[ks], A1[c1 & 1], 0, 0, 0); ++c1;
            A0[c0 & 1] = __builtin_amdgcn_mfma_f32_16x16x32_f16(ah0, bl[ks], A0[c0 & 1], 0, 0, 0); ++c0;
            A1[c1 & 1] = __builtin_amdgcn_mfma_f32_16x16x32_f16(ah1, bl[ks], A1[c1 & 1], 0, 0, 0); ++c1;
            A0[c0 & 1] = __builtin_amdgcn_mfma_f32_16x16x32_f16(al0, bh[ks], A0[c0 & 1], 0, 0, 0); ++c0;
            A1[c1 & 1] = __builtin_amdgcn_mfma_f32_16x16x32_f16(al1, bh[ks], A1[c1 & 1], 0, 0, 0); ++c1;
        }
        // epilogue tile 0
        {
            f32x4 acc;
            #pragma unroll
            for (int i = 0; i < 4; ++i) acc[i] = A0[0][i] + A0[1][i];
            float p01 = dpp_max8(fmaxf(acc[0], acc[1]));
            float p23 = dpp_max8(fmaxf(acc[2], acc[3]));
            if (dx == 0 && c < 6) {
                uint* outb = p1 + ((size_t)(n0 + im0) * 6 + c) * 196;
                int r0 = tl0 * 16 + qr * 4;
                if (r0 + 1 < 392) {
                    int qxa = (r0 * 586) >> 14, ya = r0 - qxa * 28;
                    outb[(ya >> 1) * 14 + qxa] = splitpack(fmaxf(p01 + bias, 0.f));
                }
                int r2 = r0 + 2;
                if (r2 + 1 < 392) {
                    int qxb = (r2 * 586) >> 14, yb = r2 - qxb * 28;
                    outb[(yb >> 1) * 14 + qxb] = splitpack(fmaxf(p23 + bias, 0.f));
                }
            }
        }
        // epilogue tile 1
        if (t1 != t0) {
            f32x4 acc;
            #pragma unroll
            for (int i = 0; i < 4; ++i) acc[i] = A1[0][i] + A1[1][i];
            float p01 = dpp_max8(fmaxf(acc[0], acc[1]));
            float p23 = dpp_max8(fmaxf(acc[2], acc[3]));
            if (dx == 0 && c < 6) {
                uint* outb = p1 + ((size_t)(n0 + im1) * 6 + c) * 196;
                int r0 = tl1 * 16 + qr * 4;
                if (r0 + 1 < 392) {
                    int qxa = (r0 * 586) >> 14, ya = r0 - qxa * 28;
                    outb[(ya >> 1) * 14 + qxa] = splitpack(fmaxf(p01 + bias, 0.f));
                }
                int r2 = r0 + 2;
                if (r2 + 1 < 392) {
                    int qxb = (r2 * 586) >> 14, yb = r2 - qxb * 28;
                    outb[(yb >> 1) * 14 + qxb] = splitpack(fmaxf(p23 + bias, 0.f));
                }
            }
        }
    }
}

// ---------------- conv2 via split-fp16 MFMA: p1 packed -> p2:[N,400] fp32 ----------------
__global__ __launch_bounds__(256) void k_conv2(const uint* __restrict__ p1,
                                               const float* __restrict__ w,
                                               const float* __restrict__ b,
                                               float* __restrict__ p2) {
    __shared__ uint simg[4 * 1260];
    __shared__ uint sB[5 * 64 * 8];
    __shared__ float sb[16];
    const int tid  = threadIdx.x;
    const int lane = tid & 63;
    const int wv   = tid >> 6;
    const int n0   = blockIdx.x * 4;

    for (int i = tid; i < 4704; i += 256) {
        int img = i / 1176, rem = i % 1176;
        int c = rem / 196, rr = rem % 196;
        int y = rr / 14, xx = rr % 14;
        simg[img * 1260 + c * 210 + y * 15 + xx] = p1[(size_t)(n0 + img) * 1176 + rem];
    }
    for (int p = tid; p < 320; p += 256) {
        int ks = p >> 6, l = p & 63;
        int nn = l & 15, g = l >> 4;
        #pragma unroll
        for (int j = 0; j < 8; ++j) {
            int k = ks * 32 + g * 8 + j;
            float wv_ = (k < 150) ? w[nn * 150 + k] : 0.f;
            sB[p * 8 + j] = splitpack(wv_);
        }
    }
    if (tid < 16) sb[tid] = b[tid];
    __syncthreads();

    const int qw = (lane & 15) >> 2;
    const int dy = (lane >> 1) & 1, dx = lane & 1;
    const int g  = lane >> 4;
    int offs[40];
    #pragma unroll
    for (int ks = 0; ks < 5; ++ks)
        #pragma unroll
        for (int j = 0; j < 8; ++j) {
            int k = ks * 32 + g * 8 + j;
            int o = 0;
            if (k < 150) { int ci = k / 25, r = k % 25; o = ci * 210 + (r / 5) * 15 + (r % 5); }
            offs[ks * 8 + j] = o;
        }
    half8 bh[5], bl[5];
    #pragma unroll
    for (int ks = 0; ks < 5; ++ks)
        #pragma unroll
        for (int j = 0; j < 8; ++j) {
            uint u = sB[(ks * 64 + lane) * 8 + j];
            bh[ks][j] = lo16h(u); bl[ks][j] = hi16h(u);
        }

    const uint* img = simg + wv * 1260;
    const int n  = n0 + wv;
    const int cc = lane & 15;
    const int qr = lane >> 4;
    const float bias = sb[cc];
    float* outb = p2 + (size_t)n * 400 + cc * 25;

    for (int t = 0; t < 7; ++t) {
        int qa = t * 4 + qw; if (qa > 24) qa = 24;
        int qy = qa / 5, qx = qa % 5;
        int base = (2 * qy + dy) * 15 + (2 * qx + dx);
        f32x4 acc2[2] = {{0.f,0.f,0.f,0.f},{0.f,0.f,0.f,0.f}};
        int pp = 0;
        #pragma unroll
        for (int ks = 0; ks < 5; ++ks) {
            uint up[8];
            #pragma unroll
            for (int j = 0; j < 8; ++j) up[j] = img[base + offs[ks * 8 + j]];
            half8 ah, al;
            #pragma unroll
            for (int j = 0; j < 8; ++j) { ah[j] = lo16h(up[j]); al[j] = hi16h(up[j]); }
            acc2[pp & 1] = __builtin_amdgcn_mfma_f32_16x16x32_f16(ah, bh[ks], acc2[pp & 1], 0, 0, 0); ++pp;
            acc2[pp & 1] = __builtin_amdgcn_mfma_f32_16x16x32_f16(ah, bl[ks], acc2[pp & 1], 0, 0, 0); ++pp;
            acc2[pp & 1] = __builtin_amdgcn_mfma_f32_16x16x32_f16(al, bh[ks], acc2[pp & 1], 0, 0, 0); ++pp;
        }
        int qc = t * 4 + qr;
        if (qc < 25) {
            float m = fmaxf(fmaxf(acc2[0][0] + acc2[1][0], acc2[0][1] + acc2[1][1]),
                            fmaxf(acc2[0][2] + acc2[1][2], acc2[0][3] + acc2[1][3]));
            outb[qc] = fmaxf(m + bias, 0.f);
        }
    }
}

// ---------------- fc1: [N,400] @ [120,400]^T + relu -> h1:[N,120] ----------------
__global__ __launch_bounds__(256) void k_fc1(const float* __restrict__ p2,
                                             const float* __restrict__ w,
                                             const float* __restrict__ b,
                                             float* __restrict__ h1) {
    __shared__ float sa[64 * 100];
    __shared__ float swt[120 * 101];
    const int tid = threadIdx.x;
    const int n0 = blockIdx.x * 64;
    const int tc = tid % 30, tr = tid / 30;
    float acc[8][4];
    #pragma unroll
    for (int i = 0; i < 8; ++i)
        #pragma unroll
        for (int j = 0; j < 4; ++j) acc[i][j] = 0.f;

    for (int kt = 0; kt < 4; ++kt) {
        __syncthreads();
        for (int i = tid; i < 1600; i += 256) {
            int r = i / 25, k4 = (i % 25) * 4;
            float4 v = *(const float4*)(p2 + (size_t)(n0 + r) * 400 + kt * 100 + k4);
            *(float4*)(sa + r * 100 + k4) = v;
        }
        for (int i = tid; i < 3000; i += 256) {
            int c = i / 25, k4 = (i % 25) * 4;
            float4 v = *(const float4*)(w + (size_t)c * 400 + kt * 100 + k4);
            float* d = swt + c * 101 + k4;
            d[0] = v.x; d[1] = v.y; d[2] = v.z; d[3] = v.w;
        }
        __syncthreads();
        if (tr < 8) {
            #pragma unroll 4
            for (int k = 0; k < 100; ++k) {
                float av[8], wv[4];
                #pragma unroll
                for (int i = 0; i < 8; ++i) av[i] = sa[(tr * 8 + i) * 100 + k];
                #pragma unroll
                for (int j = 0; j < 4; ++j) wv[j] = swt[(tc * 4 + j) * 101 + k];
                #pragma unroll
                for (int i = 0; i < 8; ++i)
                    #pragma unroll
                    for (int j = 0; j < 4; ++j) acc[i][j] = fmaf(av[i], wv[j], acc[i][j]);
            }
        }
    }
    if (tr < 8) {
        #pragma unroll
        for (int j = 0; j < 4; ++j) {
            const int o = tc * 4 + j;
            const float bo = b[o];
            #pragma unroll
            for (int i = 0; i < 8; ++i) {
                const int rr = n0 + tr * 8 + i;
                h1[(size_t)rr * 120 + o] = fmaxf(acc[i][j] + bo, 0.f);
            }
        }
    }
}

// ---------------- compose: C[e][o][d] = sum_j head_w[o][j]*expert_w[e][j][d] ----------------
__global__ __launch_bounds__(256) void k_compose(const float* __restrict__ ew,
                                                 const float* __restrict__ eb,
                                                 const float* __restrict__ hw,
                                                 float* __restrict__ C,
                                                 float* __restrict__ hb2) {
    __shared__ float shw[840];
    __shared__ float seb[672];
    const int e = blockIdx.x, tid = threadIdx.x;
    for (int i = tid; i < 840; i += 256) shw[i] = hw[i];
    for (int i = tid; i < 672; i += 256) seb[i] = eb[i];
    __syncthreads();
    for (int i = tid; i < 840; i += 256) {
        int o = i / 84, d = i % 84;
        float s = 0.f;
        for (int j = 0; j < 84; ++j)
            s = fmaf(shw[o * 84 + j], ew[((size_t)e * 84 + j) * 84 + d], s);
        C[e * 840 + i] = s;
    }
    if (tid < 10) {
        float s = 0.f;
        for (int j = 0; j < 84; ++j) s = fmaf(shw[tid * 84 + j], seb[e * 84 + j], s);
        hb2[e * 10 + tid] = s;
    }
}

// ---------------- tail: fc2+relu, gate, top2-softmax, MoE(composed)+head ----------------
__global__ __launch_bounds__(256) void k_tail(const float* __restrict__ h1,
                                              const float* __restrict__ f2w,
                                              const float* __restrict__ f2b,
                                              const float* __restrict__ gw,
                                              const float* __restrict__ Cw,
                                              const float* __restrict__ hb2,
                                              const float* __restrict__ headb,
                                              float* __restrict__ out) {
    __shared__ float sh1[64 * 120];
    __shared__ float sfw[84 * 121];
    __shared__ float sfb[84];
    __shared__ float sgw[672];
    __shared__ float sh[64 * 85];
    __shared__ float sC[6800];
    __shared__ float shb2[80];
    __shared__ float shb[10];
    __shared__ float slog[64 * 9];
    __shared__ float swt[128];
    __shared__ int   sei[128];
    const int tid = threadIdx.x;
    const int n0 = blockIdx.x * 64;

    {
        const float4* g = (const float4*)(h1 + (size_t)n0 * 120);
        float4* s = (float4*)sh1;
        for (int i = tid; i < 1920; i += 256) s[i] = g[i];
    }
    for (int i = tid; i < 2520; i += 256) {
        int o = i / 30, k4 = (i % 30) * 4;
        float4 v = *(const float4*)(f2w + (size_t)o * 120 + k4);
        float* d = sfw + o * 121 + k4;
        d[0] = v.x; d[1] = v.y; d[2] = v.z; d[3] = v.w;
    }
    for (int i = tid; i < 6720; i += 256) sC[(i / 84) * 85 + (i % 84)] = Cw[i];
    for (int i = tid; i < 672; i += 256) sgw[i] = gw[i];
    if (tid < 84) sfb[tid] = f2b[tid];
    if (tid < 80) shb2[tid] = hb2[tid];
    if (tid < 10) shb[tid] = headb[tid];
    __syncthreads();

    for (int i = tid; i < 5376; i += 256) {
        const int t = i / 84, o = i % 84;
        const float* a = sh1 + t * 120;
        const float* wr = sfw + o * 121;
        float s = 0.f;
        #pragma unroll 8
        for (int k = 0; k < 120; ++k) s = fmaf(a[k], wr[k], s);
        sh[t * 85 + o] = fmaxf(s + sfb[o], 0.f);
    }
    __syncthreads();

    for (int i = tid; i < 512; i += 256) {
        const int t = i / 8, e = i % 8;
        const float* a = sh + t * 85;
        float s = 0.f;
        #pragma unroll 4
        for (int d = 0; d < 84; ++d) s = fmaf(a[d], sgw[d * 8 + e], s);
        slog[t * 9 + e] = s;
    }
    __syncthreads();

    if (tid < 64) {
        const float* l = slog + tid * 9;
        float m1 = l[0]; int i1 = 0;
        #pragma unroll
        for (int e = 1; e < 8; ++e) if (l[e] > m1) { m1 = l[e]; i1 = e; }
        float m2 = -1e30f; int i2 = 0;
        #pragma unroll
        for (int e = 0; e < 8; ++e) if (e != i1 && l[e] > m2) { m2 = l[e]; i2 = e; }
        const float r = expf(m2 - m1);
        const float inv = 1.f / (1.f + r);
        swt[tid * 2] = inv; swt[tid * 2 + 1] = r * inv;
        sei[tid * 2] = i1; sei[tid * 2 + 1] = i2;
    }
    __syncthreads();

    for (int i = tid; i < 640; i += 256) {
        const int t = i / 10, o = i % 10;
        const float* a = sh + t * 85;
        const float w0 = swt[t * 2], w1 = swt[t * 2 + 1];
        const int e0 = sei[t * 2], e1 = sei[t * 2 + 1];
        const float* c0 = sC + (e0 * 10 + o) * 85;
        const float* c1 = sC + (e1 * 10 + o) * 85;
        float s0 = 0.f, s1 = 0.f;
        #pragma unroll 4
        for (int d = 0; d < 84; ++d) {
            s0 = fmaf(a[d], c0[d], s0);
            s1 = fmaf(a[d], c1[d], s1);
        }
        out[(size_t)(n0 + t) * 10 + o] =
            shb[o] + w0 * (s0 + shb2[e0 * 10 + o]) + w1 * (s1 + shb2[e1 * 10 + o]);
    }
}

extern "C" void kernel_launch(void* const* d_in, const int* in_sizes, int n_in,
                              void* d_out, int out_size, void* d_ws, size_t ws_size,
                              hipStream_t stream) {
    const float* x   = (const float*)d_in[0];
    const float* c1w = (const float*)d_in[1];
    const float* c1b = (const float*)d_in[2];
    const float* c2w = (const float*)d_in[3];
    const float* c2b = (const float*)d_in[4];
    const float* f1w = (const float*)d_in[5];
    const float* f1b = (const float*)d_in[6];
    const float* f2w = (const float*)d_in[7];
    const float* f2b = (const float*)d_in[8];
    const float* gw  = (const float*)d_in[9];
    const float* ew  = (const float*)d_in[10];
    const float* eb  = (const float*)d_in[11];
    const float* hw  = (const float*)d_in[12];
    const float* hb  = (const float*)d_in[13];
    float* out = (float*)d_out;

    const int N = in_sizes[0] / 3072;   // 16384

    float* ws = (float*)d_ws;
    uint*  p1  = (uint*)ws;                    // N*1176 uints (packed hi/lo)
    float* p2  = ws + (size_t)N * 1176;        // N*400
    float* h1  = p2 + (size_t)N * 400;         // N*120
    float* C   = h1 + (size_t)N * 120;         // 6720
    float* hb2 = C + 6720;                     // 80

    k_conv1<<<N / 2, 256, 0, stream>>>(x, c1w, c1b, p1);
    k_conv2<<<N / 4, 256, 0, stream>>>(p1, c2w, c2b, p2);
    k_fc1<<<N / 64, 256, 0, stream>>>(p2, f1w, f1b, h1);
    k_compose<<<8, 256, 0, stream>>>(ew, eb, hw, C, hb2);
    k_tail<<<N / 64, 256, 0, stream>>>(h1, f2w, f2b, gw, C, hb2, hb, out);
}